// Round 4
// baseline (971.335 us; speedup 1.0000x reference)
//
#include <hip/hip_runtime.h>

typedef __attribute__((ext_vector_type(8))) short bf16x8;
typedef __attribute__((ext_vector_type(4))) float f32x4;
typedef unsigned short u16;
typedef unsigned int u32;
typedef unsigned long long u64;

#define DEV static __device__ __forceinline__
DEV u16 f2bf(float f) { u32 i = __float_as_uint(f); i += 0x7fffu + ((i >> 16) & 1u); return (u16)(i >> 16); }
DEV float bf2f(u16 u) { return __uint_as_float(((u32)u) << 16); }

constexpr int Mn = 8192;
constexpr int Pn = 256;
constexpr int Kn = 32;
constexpr float R2 = 0.09f;

// =====================================================================
// k_voting_off v2 — bank-conflict-free + vectorized LDS access.
//   Round-3 PMC: 9.3M SQ_LDS_BANK_CONFLICT, 57% VALUBusy, 22% of fp32
//   peak. Cause: w-reads at stride-4 floats (8-way conflict, 4x b32/k)
//   + scalar x-reads. Fix (bit-exact: per-(row,col) accumulation is the
//   same ascending-k fmaf chain, identical expressions):
//   * cols per thread remapped to {2cg, 2cg+1, 128+2cg, 129+2cg} ->
//     w-read = 2x ds_read_b64, lane-consecutive -> conflict-free.
//   * Wc padded to [16][262]: staging writes conflict-free, b64 aligned.
//   * Xst padded to [256][18]: x-read = 2x broadcast ds_read_b64.
//   LDS ops per k: 8 scalar -> 4 vector; conflicts ~0.
// =====================================================================
__global__ __launch_bounds__(256) void k_voting_off(
    const float* __restrict__ sxyz,   // (65536,2)
    const float* __restrict__ sfeat,  // (65536,256)
    const float* __restrict__ ow1, const float* __restrict__ ob1,
    const float* __restrict__ os1, const float* __restrict__ ot1,
    const float* __restrict__ ow2, const float* __restrict__ ob2,
    float* __restrict__ votes)        // (65536,2)
{
  __shared__ __align__(16) float Xst[256][18];   // [k][row], pad 18
  __shared__ __align__(16) float Hst[256][17];   // [col][row]
  __shared__ __align__(16) float Wc[16][262];    // [k][col], pad 262

  const int tid = threadIdx.x;
  const int row0 = blockIdx.x * 16;

  for (int i = tid; i < 16 * 256; i += 256) {
    int r = i >> 8, c = i & 255;
    Xst[c][r] = sfeat[(row0 + r) * 256 + c];
  }
  __syncthreads();

  const int rg = tid >> 6;        // wave id 0..3
  const int ro = rg * 4;          // rows ro..ro+3
  const int cg = tid & 63;        // lane

  float acc[4][4];
#pragma unroll
  for (int r = 0; r < 4; ++r)
#pragma unroll
    for (int j = 0; j < 4; ++j) acc[r][j] = 0.f;

  for (int kc = 0; kc < 16; ++kc) {
    __syncthreads();
    for (int i = tid; i < 256 * 16; i += 256) {
      int o = i >> 4, k = i & 15;
      Wc[k][o] = ow1[o * 256 + kc * 16 + k];
    }
    __syncthreads();
#pragma unroll
    for (int k = 0; k < 16; ++k) {
      const int kk = kc * 16 + k;
      float2 xlo = *(const float2*)&Xst[kk][ro];       // broadcast b64
      float2 xhi = *(const float2*)&Xst[kk][ro + 2];   // broadcast b64
      float2 wlo = *(const float2*)&Wc[k][2 * cg];         // cols 2cg,2cg+1
      float2 whi = *(const float2*)&Wc[k][128 + 2 * cg];   // cols 128+2cg,129+2cg
      float x[4] = {xlo.x, xlo.y, xhi.x, xhi.y};
      float w[4] = {wlo.x, wlo.y, whi.x, whi.y};
#pragma unroll
      for (int r = 0; r < 4; ++r)
#pragma unroll
        for (int j = 0; j < 4; ++j)
          acc[r][j] = fmaf(x[r], w[j], acc[r][j]);
    }
  }
  __syncthreads();
#pragma unroll
  for (int j = 0; j < 4; ++j) {
    int o = (j < 2) ? (2 * cg + j) : (126 + 2 * cg + j);  // j=2:128+2cg, j=3:129+2cg
    float bb = ob1[o], ss = os1[o], tt = ot1[o];
#pragma unroll
    for (int r = 0; r < 4; ++r)
      Hst[o][ro + r] = fmaxf((acc[r][j] + bb) * ss + tt, 0.f);
  }
  __syncthreads();

  if (tid < 32) {
    int r = tid >> 1, o = tid & 1;
    float a = 0.f;
    for (int k = 0; k < 256; ++k)
      a = fmaf(Hst[k][r], ow2[o * 256 + k], a);
    a += ob2[o];
    int row = row0 + r;
    votes[row * 2 + o] = sxyz[row * 2 + o] + a;
  }
}

// =====================================================================
// k_fps v6 — software-pipelined scan (points prefetched into registers).
//   Round-3 PMC: per-CU VALUBusy ~70% (2.2% chip / 8 of 256 CUs) ->
//   VALU-issue-bound; VGPR=52 means few point-pairs in flight, so the
//   scan serialized on LDS load-use. Fixes:
//   * Prefetch next iter's 16 float2 into regs right after the scan
//     consumes the current ones — loads overlap the whole reduce+
//     barrier phase. Addresses are loop-invariant (one base reg +
//     imm offsets), zero addr VALU.
//   * Argmax chain split into 4 index-ordered subchains + ordered
//     merge (strict '>') — preserves first-max-in-index-order exactly.
//   * Winner coords via one uniform (broadcast) LDS read at the end.
//   Decisions bit-identical: same fp32 expressions, same total order
//   (dist desc, idx asc), partition/associativity invariant.
// =====================================================================
__global__ __launch_bounds__(512, 1) void k_fps(
    const float* __restrict__ votes, float* __restrict__ nxyz,
    float* __restrict__ out)
{
  const int b = blockIdx.x, tid = threadIdx.x;
  const float* vb = votes + b * Mn * 2;
  __shared__ __align__(16) float2 xy[Mn];          // 65536 B
  __shared__ u32 Sd[2][32], Sl[2][32];
  __shared__ float histx[256], histy[256];

  {
    const float4* vb4 = (const float4*)vb;
#pragma unroll
    for (int j = tid; j < Mn / 2; j += 512) {
      *(float4*)&xy[2 * j] = vb4[j];
    }
  }
  float dist[16];
#pragma unroll
  for (int s = 0; s < 16; ++s) dist[s] = 1e10f;
  __syncthreads();

  float cx = xy[0].x, cy = xy[0].y;
  if (tid == 0) { histx[0] = cx; histy[0] = cy; }

  // initial prefetch of this thread's 16 points
  float pxr[16], pyr[16];
#pragma unroll
  for (int s = 0; s < 16; ++s) {
    float2 p = xy[s * 512 + tid];
    pxr[s] = p.x; pyr[s] = p.y;
  }
#pragma unroll
  for (int s = 0; s < 16; ++s) asm volatile("" : "+v"(pxr[s]), "+v"(pyr[s]));

  for (int it = 1; it < Pn; ++it) {
    // 4 independent index-ordered subchains (ILP), merged in order.
    float bdc[4]; int sbc[4];
#pragma unroll
    for (int c = 0; c < 4; ++c) {
      float bdl = -1.f; int sbl = 4 * c;
#pragma unroll
      for (int q = 0; q < 4; ++q) {
        int s = 4 * c + q;
        float dx = pxr[s] - cx, dy = pyr[s] - cy;
        float d = fminf(dist[s], dx * dx + dy * dy);
        dist[s] = d;
        if (d > bdl) { bdl = d; sbl = s; }
      }
      bdc[c] = bdl; sbc[c] = sbl;
    }
    float bd = bdc[0]; int sb = sbc[0];
    if (bdc[1] > bd) { bd = bdc[1]; sb = sbc[1]; }
    if (bdc[2] > bd) { bd = bdc[2]; sb = sbc[2]; }
    if (bdc[3] > bd) { bd = bdc[3]; sb = sbc[3]; }

    // prefetch for NEXT iteration — overlaps the reduce/barrier phase
#pragma unroll
    for (int s = 0; s < 16; ++s) {
      float2 p = xy[s * 512 + tid];
      pxr[s] = p.x; pyr[s] = p.y;
    }
#pragma unroll
    for (int s = 0; s < 16; ++s) asm volatile("" : "+v"(pxr[s]), "+v"(pyr[s]));

    // lexicographic key: (float bits of d, ~idx); d >= 0 so unsigned
    // bit-compare == float compare; max(~idx) == min(idx).
    int bi = sb * 512 + tid;
    u32 hd = __float_as_uint(bd), hl = ~(u32)bi;

#define FPS_ROR(VD, VL, N)                                                      \
    {                                                                           \
      u32 od = (u32)__builtin_amdgcn_update_dpp(0, (int)VD, 0x120 + N, 0xF, 0xF, false); \
      u32 ol = (u32)__builtin_amdgcn_update_dpp(0, (int)VL, 0x120 + N, 0xF, 0xF, false); \
      bool g = (od > VD) || (od == VD && ol > VL);                              \
      VD = g ? od : VD; VL = g ? ol : VL;                                       \
    }
    FPS_ROR(hd, hl, 8)
    FPS_ROR(hd, hl, 4)
    FPS_ROR(hd, hl, 2)
    FPS_ROR(hd, hl, 1)

    const int buf = it & 1;
    if ((tid & 15) == 0) {
      int row = tid >> 4;              // 0..31
      Sd[buf][row] = hd; Sl[buf][row] = hl;
    }
    __syncthreads();

    int rr = tid & 15;
    u32 rd = Sd[buf][rr], rl = Sl[buf][rr];
    {
      u32 od = Sd[buf][16 + rr], ol = Sl[buf][16 + rr];
      bool g = (od > rd) || (od == rd && ol > rl);
      rd = g ? od : rd; rl = g ? ol : rl;
    }
    FPS_ROR(rd, rl, 8)
    FPS_ROR(rd, rl, 4)
    FPS_ROR(rd, rl, 2)
    FPS_ROR(rd, rl, 1)
#undef FPS_ROR

    int widx = (int)(~rl);
    float2 w = xy[widx];               // uniform addr -> LDS broadcast
    cx = w.x; cy = w.y;
    if (tid == 0) { histx[it] = cx; histy[it] = cy; }
  }
  __syncthreads();
  if (tid < 256) {
    float2 o2; o2.x = histx[tid]; o2.y = histy[tid];
    *(float2*)&nxyz[(b * Pn + tid) * 2] = o2;
    *(float2*)&out[(b * Pn + tid) * 2] = o2;
  }
}

// =====================================================================
// Ball query — round 7 verbatim (proven).
// =====================================================================
__global__ __launch_bounds__(256) void k_ballq(
    const float* __restrict__ votes, const float* __restrict__ nxyz,
    int* __restrict__ gidx)
{
  const int bp = blockIdx.x, tid = threadIdx.x;
  const int b = bp >> 8;
  const float* vb = votes + b * Mn * 2;
  const float sx = nxyz[bp * 2], sy = nxyz[bp * 2 + 1];
  const float a = sx * sx + sy * sy;
  float d2[32];
#pragma unroll
  for (int s = 0; s < 32; ++s) {
    int i = tid * 32 + s;
    float x = vb[i * 2], y = vb[i * 2 + 1];
    d2[s] = (a + (x * x + y * y)) - 2.f * (sx * x + sy * y);
  }
  __shared__ float sd[4];
  __shared__ int si[4];
  __shared__ int swi;
  unsigned mask = 0;
  for (int kk = 0; kk < Kn; ++kk) {
    float bd = 3.4e38f; int bi = 0x7fffffff;
#pragma unroll
    for (int s = 0; s < 32; ++s)
      if (!((mask >> s) & 1u) && d2[s] < bd) { bd = d2[s]; bi = tid * 32 + s; }
#pragma unroll
    for (int off = 32; off > 0; off >>= 1) {
      float od = __shfl_xor(bd, off);
      int oi = __shfl_xor(bi, off);
      if (od < bd || (od == bd && oi < bi)) { bd = od; bi = oi; }
    }
    if ((tid & 63) == 0) { sd[tid >> 6] = bd; si[tid >> 6] = bi; }
    __syncthreads();
    if (tid == 0) {
#pragma unroll
      for (int w = 1; w < 4; ++w)
        if (sd[w] < bd || (sd[w] == bd && si[w] < bi)) { bd = sd[w]; bi = si[w]; }
      swi = bi;
      gidx[bp * Kn + kk] = (bd > R2) ? 0 : bi;
    }
    __syncthreads();
    int wi = swi;
    if ((wi >> 5) == tid) mask |= 1u << (wi & 31);
  }
}

// =====================================================================
// Prep: bf16 weight conversions (after the discrete path).
// =====================================================================
__global__ __launch_bounds__(256) void k_prep(
    const float* __restrict__ fw1, const float* __restrict__ fw2,
    const float* __restrict__ aw1, const float* __restrict__ aw2,
    u16* __restrict__ FW1h, u16* __restrict__ FW2b,
    u16* __restrict__ AW1b, u16* __restrict__ AW2b)
{
  const int gid = blockIdx.x * 256 + threadIdx.x;
  const int gsz = gridDim.x * 256;
  for (int i = gid; i < 65536; i += gsz) FW1h[i] = f2bf(fw1[i]);
  for (int i = gid; i < 32768; i += gsz) FW2b[i] = f2bf(fw2[i]);
  for (int i = gid; i < 65536; i += gsz) AW2b[i] = f2bf(aw2[i]);
  for (int i = gid; i < 49152; i += gsz) {
    int o = i / 192, k = i % 192;
    AW1b[i] = (k < 130) ? f2bf(aw1[o * 130 + k]) : (u16)0;
  }
}

// =====================================================================
// k_vf — round 7 verbatim (proven).
// =====================================================================
__global__ __launch_bounds__(256) void k_vf(
    const float* __restrict__ sfeat, const u16* __restrict__ FW1h,
    const float* __restrict__ fb1, const float* __restrict__ fs1,
    const float* __restrict__ ft1, const u16* __restrict__ FW2b,
    const float* __restrict__ fb2, u16* __restrict__ vfeat)
{
  __shared__ u16 Hs[128 * 136];
  __shared__ u16 As[128 * 40];
  __shared__ u16 Bs[128 * 40];
  const int tid = threadIdx.x;
  const int row0 = blockIdx.x * 128;
  const int wid = tid >> 6, lane = tid & 63, m16 = lane & 15, quad = lane >> 4;
  const int wr = wid >> 1, wc = wid & 1;
  const int sr = tid >> 1, sk = (tid & 1) * 16;

  f32x4 acc2[4][4];
#pragma unroll
  for (int mt = 0; mt < 4; ++mt)
#pragma unroll
    for (int nt = 0; nt < 4; ++nt) acc2[mt][nt] = (f32x4){0.f, 0.f, 0.f, 0.f};

  for (int h = 0; h < 2; ++h) {
    f32x4 acc[4][4];
#pragma unroll
    for (int mt = 0; mt < 4; ++mt)
#pragma unroll
      for (int nt = 0; nt < 4; ++nt) acc[mt][nt] = (f32x4){0.f, 0.f, 0.f, 0.f};

    for (int s = 0; s < 8; ++s) {
      __syncthreads();
      {
        const float* src = &sfeat[(row0 + sr) * 256 + s * 32 + sk];
        u32 packed[8];
#pragma unroll
        for (int q = 0; q < 4; ++q) {
          float4 v = *(const float4*)&src[q * 4];
          packed[q * 2]     = (u32)f2bf(v.x) | ((u32)f2bf(v.y) << 16);
          packed[q * 2 + 1] = (u32)f2bf(v.z) | ((u32)f2bf(v.w) << 16);
        }
        *(uint4*)&As[sr * 40 + sk]     = *(uint4*)&packed[0];
        *(uint4*)&As[sr * 40 + sk + 8] = *(uint4*)&packed[4];
        const u16* bsrc = &FW1h[(h * 128 + sr) * 256 + s * 32 + sk];
        *(uint4*)&Bs[sr * 40 + sk]     = *(const uint4*)&bsrc[0];
        *(uint4*)&Bs[sr * 40 + sk + 8] = *(const uint4*)&bsrc[8];
      }
      __syncthreads();
#pragma unroll
      for (int mt = 0; mt < 4; ++mt) {
        bf16x8 af = *(const bf16x8*)&As[(wr * 64 + mt * 16 + m16) * 40 + quad * 8];
#pragma unroll
        for (int nt = 0; nt < 4; ++nt) {
          bf16x8 bfr = *(const bf16x8*)&Bs[(wc * 64 + nt * 16 + m16) * 40 + quad * 8];
          acc[mt][nt] = __builtin_amdgcn_mfma_f32_16x16x32_bf16(af, bfr, acc[mt][nt], 0, 0, 0);
        }
      }
    }
    __syncthreads();
#pragma unroll
    for (int nt = 0; nt < 4; ++nt) {
      int colL = wc * 64 + nt * 16 + m16;
      int col = h * 128 + colL;
      float bb = fb1[col], ss = fs1[col], tt = ft1[col];
#pragma unroll
      for (int mt = 0; mt < 4; ++mt) {
        int rL = wr * 64 + mt * 16 + quad * 4;
#pragma unroll
        for (int r = 0; r < 4; ++r)
          Hs[(rL + r) * 136 + colL] = f2bf(fmaxf((acc[mt][nt][r] + bb) * ss + tt, 0.f));
      }
    }
    for (int s2 = 0; s2 < 4; ++s2) {
      __syncthreads();
      {
        const u16* bsrc = &FW2b[sr * 256 + h * 128 + s2 * 32 + sk];
        *(uint4*)&Bs[sr * 40 + sk]     = *(const uint4*)&bsrc[0];
        *(uint4*)&Bs[sr * 40 + sk + 8] = *(const uint4*)&bsrc[8];
      }
      __syncthreads();
#pragma unroll
      for (int mt = 0; mt < 4; ++mt) {
        bf16x8 af = *(const bf16x8*)&Hs[(wr * 64 + mt * 16 + m16) * 136 + s2 * 32 + quad * 8];
#pragma unroll
        for (int nt = 0; nt < 4; ++nt) {
          bf16x8 bfr = *(const bf16x8*)&Bs[(wc * 64 + nt * 16 + m16) * 40 + quad * 8];
          acc2[mt][nt] = __builtin_amdgcn_mfma_f32_16x16x32_bf16(af, bfr, acc2[mt][nt], 0, 0, 0);
        }
      }
    }
  }
#pragma unroll
  for (int nt = 0; nt < 4; ++nt) {
    int col = wc * 64 + nt * 16 + m16;
    float bb = fb2[col];
#pragma unroll
    for (int mt = 0; mt < 4; ++mt) {
      int rbase = row0 + wr * 64 + mt * 16 + quad * 4;
#pragma unroll
      for (int r = 0; r < 4; ++r)
        vfeat[(rbase + r) * 128 + col] = f2bf(acc2[mt][nt][r] + bb);
    }
  }
}

// =====================================================================
// k_agg — round 7 verbatim (proven).
// =====================================================================
__global__ __launch_bounds__(256) void k_agg(
    const float* __restrict__ votes, const u16* __restrict__ vfeat,
    const float* __restrict__ nxyz, const int* __restrict__ gidx,
    const u16* __restrict__ AW1b, const float* __restrict__ ab1,
    const float* __restrict__ as1, const float* __restrict__ at1,
    const u16* __restrict__ AW2b, const float* __restrict__ ab2,
    const float* __restrict__ as2, const float* __restrict__ at2,
    float* __restrict__ pooled)
{
  __shared__ u16 U[32 * 264];
  __shared__ u16 Bs[256 * 72];
  __shared__ int gix[32];
  __shared__ float gvx[32], gvy[32];
  u16* CombA = U;
  u16* As = U;
  float* x2T = (float*)Bs;

  const int bp = blockIdx.x, tid = threadIdx.x, b = bp >> 8;
  if (tid < 32) {
    int g = gidx[bp * 32 + tid];
    gix[tid] = g;
    gvx[tid] = votes[(b * Mn + g) * 2];
    gvy[tid] = votes[(b * Mn + g) * 2 + 1];
  }
  __syncthreads();
  const float sx = nxyz[bp * 2], sy = nxyz[bp * 2 + 1];

  if (tid < 192) {
    int row = tid / 6, c = tid % 6;
    const u16* vsrc = &vfeat[(b * Mn + gix[row]) * 128];
    u16* dst = &CombA[row * 200 + c * 32];
    if (c == 0) {
      dst[0] = f2bf(gvx[row] - sx);
      dst[1] = f2bf(gvy[row] - sy);
      for (int k = 2; k < 32; ++k) dst[k] = vsrc[k - 2];
    } else if (c <= 3) {
      for (int k = 0; k < 32; ++k) dst[k] = vsrc[c * 32 + k - 2];
    } else if (c == 4) {
      dst[0] = vsrc[126]; dst[1] = vsrc[127];
      for (int k = 2; k < 32; ++k) dst[k] = 0;
    } else {
      for (int k = 0; k < 32; ++k) dst[k] = 0;
    }
  }

  const int wid = tid >> 6, lane = tid & 63, m16 = lane & 15, quad = lane >> 4;
  const int mt = wid & 1, nh = wid >> 1;

  f32x4 acc[8];
#pragma unroll
  for (int nt = 0; nt < 8; ++nt) acc[nt] = (f32x4){0.f, 0.f, 0.f, 0.f};
  for (int s = 0; s < 3; ++s) {
    __syncthreads();
    for (int i = tid; i < 4096; i += 256) {
      int n = i >> 4, c4 = i & 15;
      *(uint2*)&Bs[n * 72 + c4 * 4] = *(const uint2*)&AW1b[n * 192 + s * 64 + c4 * 4];
    }
    __syncthreads();
#pragma unroll
    for (int ks = 0; ks < 2; ++ks) {
      bf16x8 af = *(const bf16x8*)&CombA[(mt * 16 + m16) * 200 + s * 64 + ks * 32 + quad * 8];
#pragma unroll
      for (int nt = 0; nt < 8; ++nt) {
        bf16x8 bf_ = *(const bf16x8*)&Bs[(nh * 128 + nt * 16 + m16) * 72 + ks * 32 + quad * 8];
        acc[nt] = __builtin_amdgcn_mfma_f32_16x16x32_bf16(af, bf_, acc[nt], 0, 0, 0);
      }
    }
  }
  __syncthreads();
#pragma unroll
  for (int nt = 0; nt < 8; ++nt) {
    int col = nh * 128 + nt * 16 + m16;
    float bb = ab1[col], ss = as1[col], tt = at1[col];
#pragma unroll
    for (int r = 0; r < 4; ++r) {
      int samp = mt * 16 + quad * 4 + r;
      As[samp * 264 + col] = f2bf(fmaxf((acc[nt][r] + bb) * ss + tt, 0.f));
    }
  }

  f32x4 acc2[8];
#pragma unroll
  for (int nt = 0; nt < 8; ++nt) acc2[nt] = (f32x4){0.f, 0.f, 0.f, 0.f};
  for (int s = 0; s < 4; ++s) {
    __syncthreads();
    for (int i = tid; i < 4096; i += 256) {
      int n = i >> 4, c4 = i & 15;
      *(uint2*)&Bs[n * 72 + c4 * 4] = *(const uint2*)&AW2b[n * 256 + s * 64 + c4 * 4];
    }
    __syncthreads();
#pragma unroll
    for (int ks = 0; ks < 2; ++ks) {
      bf16x8 af = *(const bf16x8*)&As[(mt * 16 + m16) * 264 + s * 64 + ks * 32 + quad * 8];
#pragma unroll
      for (int nt = 0; nt < 8; ++nt) {
        bf16x8 bf_ = *(const bf16x8*)&Bs[(nh * 128 + nt * 16 + m16) * 72 + ks * 32 + quad * 8];
        acc2[nt] = __builtin_amdgcn_mfma_f32_16x16x32_bf16(af, bf_, acc2[nt], 0, 0, 0);
      }
    }
  }
  __syncthreads();
#pragma unroll
  for (int nt = 0; nt < 8; ++nt) {
    int col = nh * 128 + nt * 16 + m16;
    float bb = ab2[col], ss = as2[col], tt = at2[col];
#pragma unroll
    for (int r = 0; r < 4; ++r) {
      int samp = mt * 16 + quad * 4 + r;
      x2T[col * 33 + samp] = fmaxf((acc2[nt][r] + bb) * ss + tt, 0.f);
    }
  }
  __syncthreads();
  {
    float m = x2T[tid * 33];
#pragma unroll
    for (int s2 = 1; s2 < 32; ++s2) m = fmaxf(m, x2T[tid * 33 + s2]);
    pooled[bp * 256 + tid] = m;
  }
}

// =====================================================================
// Proposal head — round 7 verbatim (proven).
// =====================================================================
__global__ __launch_bounds__(256) void k_head(
    const float* __restrict__ pooled,
    const float* __restrict__ pw1, const float* __restrict__ pb1,
    const float* __restrict__ ps1, const float* __restrict__ pt1,
    const float* __restrict__ pw2, const float* __restrict__ pb2,
    const float* __restrict__ ps2, const float* __restrict__ pt2,
    const float* __restrict__ objw, const float* __restrict__ objb,
    const float* __restrict__ clsw, const float* __restrict__ clsb,
    float* __restrict__ out)
{
  __shared__ float xr[256], y1[256], y2[128];
  const int bp = blockIdx.x, tid = threadIdx.x;
  xr[tid] = pooled[bp * 256 + tid];
  __syncthreads();
  {
    float a = 0.f;
    for (int c = 0; c < 256; ++c) a = fmaf(xr[c], pw1[tid * 256 + c], a);
    a = (a + pb1[tid]) * ps1[tid] + pt1[tid];
    y1[tid] = fmaxf(a, 0.f);
  }
  __syncthreads();
  if (tid < 128) {
    float a = 0.f;
    for (int c = 0; c < 256; ++c) a = fmaf(y1[c], pw2[tid * 256 + c], a);
    a = (a + pb2[tid]) * ps2[tid] + pt2[tid];
    y2[tid] = fmaxf(a, 0.f);
  }
  __syncthreads();
  if (tid < 10) {
    float a = 0.f;
    for (int c = 0; c < 128; ++c) a = fmaf(y2[c], clsw[tid * 128 + c], a);
    out[6144 + bp * 10 + tid] = a + clsb[tid];
  } else if (tid == 10) {
    float a = 0.f;
    for (int c = 0; c < 128; ++c) a = fmaf(y2[c], objw[c], a);
    out[4096 + bp] = a + objb[0];
  }
}

// =====================================================================
extern "C" void kernel_launch(void* const* d_in, const int* in_sizes, int n_in,
                              void* d_out, int out_size, void* d_ws, size_t ws_size,
                              hipStream_t stream)
{
  (void)in_sizes; (void)n_in; (void)out_size; (void)ws_size;
  const float* sxyz  = (const float*)d_in[0];
  const float* sfeat = (const float*)d_in[1];
  const float* ow1 = (const float*)d_in[2];
  const float* ob1 = (const float*)d_in[3];
  const float* os1 = (const float*)d_in[4];
  const float* ot1 = (const float*)d_in[5];
  const float* ow2 = (const float*)d_in[6];
  const float* ob2 = (const float*)d_in[7];
  const float* fw1 = (const float*)d_in[8];
  const float* fb1 = (const float*)d_in[9];
  const float* fs1 = (const float*)d_in[10];
  const float* ft1 = (const float*)d_in[11];
  const float* fw2 = (const float*)d_in[12];
  const float* fb2 = (const float*)d_in[13];
  const float* aw1 = (const float*)d_in[14];
  const float* ab1 = (const float*)d_in[15];
  const float* as1 = (const float*)d_in[16];
  const float* at1 = (const float*)d_in[17];
  const float* aw2 = (const float*)d_in[18];
  const float* ab2 = (const float*)d_in[19];
  const float* as2 = (const float*)d_in[20];
  const float* at2 = (const float*)d_in[21];
  const float* pw1 = (const float*)d_in[22];
  const float* pb1 = (const float*)d_in[23];
  const float* ps1 = (const float*)d_in[24];
  const float* pt1 = (const float*)d_in[25];
  const float* pw2 = (const float*)d_in[26];
  const float* pb2 = (const float*)d_in[27];
  const float* ps2 = (const float*)d_in[28];
  const float* pt2 = (const float*)d_in[29];
  const float* objw = (const float*)d_in[30];
  const float* objb = (const float*)d_in[31];
  const float* clsw = (const float*)d_in[32];
  const float* clsb = (const float*)d_in[33];

  char* ws = (char*)d_ws;
  float* votes  = (float*)(ws + 0);             //    524,288
  u16*   vfeat  = (u16*)  (ws + 524288);        // 16,777,216
  float* nxyz   = (float*)(ws + 17301504);      //     16,384
  int*   gidxp  = (int*)  (ws + 17317888);      //    262,144
  float* pooled = (float*)(ws + 17580032);      //  2,097,152
  u16*   FW1h   = (u16*)  (ws + 19677184);      //    131,072
  u16*   FW2b   = (u16*)  (ws + 19808256);      //     65,536
  u16*   AW1b   = (u16*)  (ws + 19873792);      //     98,304
  u16*   AW2b   = (u16*)  (ws + 19972096);      //    131,072
  float* out    = (float*)d_out;

  k_voting_off<<<dim3(4096), dim3(256), 0, stream>>>(
      sxyz, sfeat, ow1, ob1, os1, ot1, ow2, ob2, votes);

  k_fps<<<dim3(8), dim3(512), 0, stream>>>(votes, nxyz, out);

  k_ballq<<<dim3(2048), dim3(256), 0, stream>>>(votes, nxyz, gidxp);

  k_prep<<<dim3(256), dim3(256), 0, stream>>>(
      fw1, fw2, aw1, aw2, FW1h, FW2b, AW1b, AW2b);

  k_vf<<<dim3(512), dim3(256), 0, stream>>>(
      sfeat, FW1h, fb1, fs1, ft1, FW2b, fb2, vfeat);

  k_agg<<<dim3(2048), dim3(256), 0, stream>>>(
      votes, vfeat, nxyz, gidxp, AW1b, ab1, as1, at1,
      AW2b, ab2, as2, at2, pooled);

  k_head<<<dim3(2048), dim3(256), 0, stream>>>(
      pooled, pw1, pb1, ps1, pt1, pw2, pb2, ps2, pt2,
      objw, objb, clsw, clsb, out);
}

// Round 5
// 938.212 us; speedup vs baseline: 1.0353x; 1.0353x over previous
//
#include <hip/hip_runtime.h>

typedef __attribute__((ext_vector_type(8))) short bf16x8;
typedef __attribute__((ext_vector_type(4))) float f32x4;
typedef unsigned short u16;
typedef unsigned int u32;
typedef unsigned long long u64;

#define DEV static __device__ __forceinline__
DEV u16 f2bf(float f) { u32 i = __float_as_uint(f); i += 0x7fffu + ((i >> 16) & 1u); return (u16)(i >> 16); }
DEV float bf2f(u16 u) { return __uint_as_float(((u32)u) << 16); }

constexpr int Mn = 8192;
constexpr int Pn = 256;
constexpr int Kn = 32;
constexpr float R2 = 0.09f;

// =====================================================================
// k_voting_off v3 — 32 rows/block, k-chunked X+W staging.
//   Round-4 post-mortem: conflict fix (9.3M->786K) moved nothing ->
//   bottleneck is FMA-issue + staging amortization, not conflicts.
//   Chip FMA floor = 8.6GF/157TF = 55us; v2 at 258us because 16-row
//   blocks amortize 256KB W-staging + 32 barriers poorly.
//   v3: 32 rows/block (grid 2048), wave=8 rows, acc[8][4]; X staged
//   per-k-chunk (Xc[16][34]) beside Wc. FMA/k per thread doubles to 32;
//   staging per output row halves. Bit-exact: per-(row,col) ascending-k
//   fmaf chain, identical epilogue expr, identical serial 256-chain for
//   votes (64 threads now: 32 rows x 2 outputs).
// =====================================================================
__global__ __launch_bounds__(256, 2) void k_voting_off(
    const float* __restrict__ sxyz,   // (65536,2)
    const float* __restrict__ sfeat,  // (65536,256)
    const float* __restrict__ ow1, const float* __restrict__ ob1,
    const float* __restrict__ os1, const float* __restrict__ ot1,
    const float* __restrict__ ow2, const float* __restrict__ ob2,
    float* __restrict__ votes)        // (65536,2)
{
  __shared__ __align__(16) float Xc[16][34];     // [k][row], pad
  __shared__ __align__(16) float Wc[16][262];    // [k][col], pad
  __shared__ __align__(16) float Hst[256][33];   // [col][row], pad

  const int tid = threadIdx.x;
  const int row0 = blockIdx.x * 32;

  const int wv = tid >> 6;        // wave 0..3 -> rows wv*8..wv*8+7
  const int w8 = wv * 8;
  const int cg = tid & 63;        // lane -> cols {2cg,2cg+1,128+2cg,129+2cg}

  float acc[8][4];
#pragma unroll
  for (int r = 0; r < 8; ++r)
#pragma unroll
    for (int j = 0; j < 4; ++j) acc[r][j] = 0.f;

  for (int kc = 0; kc < 16; ++kc) {
    __syncthreads();
    // stage W chunk: Wc[k][o] = ow1[o*256 + kc*16 + k]
    for (int i = tid; i < 256 * 16; i += 256) {
      int o = i >> 4, k = i & 15;
      Wc[k][o] = ow1[o * 256 + kc * 16 + k];
    }
    // stage X chunk: Xc[k][r] = sfeat[(row0+r)*256 + kc*16 + k]
    for (int i = tid; i < 32 * 16; i += 256) {
      int r = i >> 4, k = i & 15;
      Xc[k][r] = sfeat[(row0 + r) * 256 + kc * 16 + k];
    }
    __syncthreads();
#pragma unroll
    for (int k = 0; k < 16; ++k) {
      float2 x01 = *(const float2*)&Xc[k][w8];
      float2 x23 = *(const float2*)&Xc[k][w8 + 2];
      float2 x45 = *(const float2*)&Xc[k][w8 + 4];
      float2 x67 = *(const float2*)&Xc[k][w8 + 6];
      float2 wlo = *(const float2*)&Wc[k][2 * cg];
      float2 whi = *(const float2*)&Wc[k][128 + 2 * cg];
      float x[8] = {x01.x, x01.y, x23.x, x23.y, x45.x, x45.y, x67.x, x67.y};
      float w[4] = {wlo.x, wlo.y, whi.x, whi.y};
#pragma unroll
      for (int r = 0; r < 8; ++r)
#pragma unroll
        for (int j = 0; j < 4; ++j)
          acc[r][j] = fmaf(x[r], w[j], acc[r][j]);
    }
  }
  __syncthreads();
#pragma unroll
  for (int j = 0; j < 4; ++j) {
    int o = (j < 2) ? (2 * cg + j) : (126 + 2 * cg + j);  // j=2:128+2cg, j=3:129+2cg
    float bb = ob1[o], ss = os1[o], tt = ot1[o];
#pragma unroll
    for (int r = 0; r < 8; ++r)
      Hst[o][w8 + r] = fmaxf((acc[r][j] + bb) * ss + tt, 0.f);
  }
  __syncthreads();

  if (tid < 64) {
    int r = tid >> 1, o = tid & 1;
    float a = 0.f;
    for (int k = 0; k < 256; ++k)
      a = fmaf(Hst[k][r], ow2[o * 256 + k], a);
    a += ob2[o];
    int row = row0 + r;
    votes[row * 2 + o] = sxyz[row * 2 + o] + a;
  }
}

// =====================================================================
// k_fps v5 — round-3 proven (241us). Points in LDS; DPP reduce.
// =====================================================================
__global__ __launch_bounds__(512, 1) void k_fps(
    const float* __restrict__ votes, float* __restrict__ nxyz,
    float* __restrict__ out)
{
  const int b = blockIdx.x, tid = threadIdx.x;
  const float* vb = votes + b * Mn * 2;
  __shared__ float2 xy[Mn];          // 65536 B
  __shared__ u32 Sd[2][32], Sl[2][32];
  __shared__ float histx[256], histy[256];

  // stage points: coalesced float4 global -> linear LDS
  {
    const float4* vb4 = (const float4*)vb;
#pragma unroll
    for (int j = tid; j < Mn / 2; j += 512) {
      float4 v = vb4[j];
      *(float4*)&xy[2 * j] = v;
    }
  }
  float dist[16];
#pragma unroll
  for (int s = 0; s < 16; ++s) dist[s] = 1e10f;
  __syncthreads();

  float cx = xy[0].x, cy = xy[0].y;
  if (tid == 0) { histx[0] = cx; histy[0] = cy; }

  for (int it = 1; it < Pn; ++it) {
    // per-thread scan over pts s*512+tid (same update expr as round 7)
    float bd = -1.f; int sb = 0;
#pragma unroll
    for (int s = 0; s < 16; ++s) {
      float2 p = xy[s * 512 + tid];
      float dx = p.x - cx, dy = p.y - cy;
      float d = fminf(dist[s], dx * dx + dy * dy);
      dist[s] = d;
      if (d > bd) { bd = d; sb = s; }
    }
    int bi = sb * 512 + tid;

    // lexicographic key: (float bits of d, ~idx); d >= 0 so unsigned
    // bit-compare == float compare; max(~idx) == min(idx).
    u32 hd = __float_as_uint(bd), hl = ~(u32)bi;

#define FPS_ROR(VD, VL, N)                                                      \
    {                                                                           \
      u32 od = (u32)__builtin_amdgcn_update_dpp(0, (int)VD, 0x120 + N, 0xF, 0xF, false); \
      u32 ol = (u32)__builtin_amdgcn_update_dpp(0, (int)VL, 0x120 + N, 0xF, 0xF, false); \
      bool g = (od > VD) || (od == VD && ol > VL);                              \
      VD = g ? od : VD; VL = g ? ol : VL;                                       \
    }
    // 16-lane all-reduce #1
    FPS_ROR(hd, hl, 8)
    FPS_ROR(hd, hl, 4)
    FPS_ROR(hd, hl, 2)
    FPS_ROR(hd, hl, 1)

    const int buf = it & 1;
    if ((tid & 15) == 0) {
      int row = tid >> 4;              // 0..31
      Sd[buf][row] = hd; Sl[buf][row] = hl;
    }
    __syncthreads();

    int rr = tid & 15;
    u32 rd = Sd[buf][rr], rl = Sl[buf][rr];
    {
      u32 od = Sd[buf][16 + rr], ol = Sl[buf][16 + rr];
      bool g = (od > rd) || (od == rd && ol > rl);
      rd = g ? od : rd; rl = g ? ol : rl;
    }
    // 16-lane all-reduce #2 over the 32 row winners (pair-merged)
    FPS_ROR(rd, rl, 8)
    FPS_ROR(rd, rl, 4)
    FPS_ROR(rd, rl, 2)
    FPS_ROR(rd, rl, 1)
#undef FPS_ROR

    int widx = (int)(~rl);
    float2 w = xy[widx];               // uniform addr -> LDS broadcast
    cx = w.x; cy = w.y;
    if (tid == 0) { histx[it] = cx; histy[it] = cy; }
  }
  __syncthreads();
  if (tid < 256) {
    float2 o2; o2.x = histx[tid]; o2.y = histy[tid];
    *(float2*)&nxyz[(b * Pn + tid) * 2] = o2;
    *(float2*)&out[(b * Pn + tid) * 2] = o2;
  }
}

// =====================================================================
// Ball query — round 7 verbatim (proven).
// =====================================================================
__global__ __launch_bounds__(256) void k_ballq(
    const float* __restrict__ votes, const float* __restrict__ nxyz,
    int* __restrict__ gidx)
{
  const int bp = blockIdx.x, tid = threadIdx.x;
  const int b = bp >> 8;
  const float* vb = votes + b * Mn * 2;
  const float sx = nxyz[bp * 2], sy = nxyz[bp * 2 + 1];
  const float a = sx * sx + sy * sy;
  float d2[32];
#pragma unroll
  for (int s = 0; s < 32; ++s) {
    int i = tid * 32 + s;
    float x = vb[i * 2], y = vb[i * 2 + 1];
    d2[s] = (a + (x * x + y * y)) - 2.f * (sx * x + sy * y);
  }
  __shared__ float sd[4];
  __shared__ int si[4];
  __shared__ int swi;
  unsigned mask = 0;
  for (int kk = 0; kk < Kn; ++kk) {
    float bd = 3.4e38f; int bi = 0x7fffffff;
#pragma unroll
    for (int s = 0; s < 32; ++s)
      if (!((mask >> s) & 1u) && d2[s] < bd) { bd = d2[s]; bi = tid * 32 + s; }
#pragma unroll
    for (int off = 32; off > 0; off >>= 1) {
      float od = __shfl_xor(bd, off);
      int oi = __shfl_xor(bi, off);
      if (od < bd || (od == bd && oi < bi)) { bd = od; bi = oi; }
    }
    if ((tid & 63) == 0) { sd[tid >> 6] = bd; si[tid >> 6] = bi; }
    __syncthreads();
    if (tid == 0) {
#pragma unroll
      for (int w = 1; w < 4; ++w)
        if (sd[w] < bd || (sd[w] == bd && si[w] < bi)) { bd = sd[w]; bi = si[w]; }
      swi = bi;
      gidx[bp * Kn + kk] = (bd > R2) ? 0 : bi;
    }
    __syncthreads();
    int wi = swi;
    if ((wi >> 5) == tid) mask |= 1u << (wi & 31);
  }
}

// =====================================================================
// Prep: bf16 weight conversions (after the discrete path).
// =====================================================================
__global__ __launch_bounds__(256) void k_prep(
    const float* __restrict__ fw1, const float* __restrict__ fw2,
    const float* __restrict__ aw1, const float* __restrict__ aw2,
    u16* __restrict__ FW1h, u16* __restrict__ FW2b,
    u16* __restrict__ AW1b, u16* __restrict__ AW2b)
{
  const int gid = blockIdx.x * 256 + threadIdx.x;
  const int gsz = gridDim.x * 256;
  for (int i = gid; i < 65536; i += gsz) FW1h[i] = f2bf(fw1[i]);
  for (int i = gid; i < 32768; i += gsz) FW2b[i] = f2bf(fw2[i]);
  for (int i = gid; i < 65536; i += gsz) AW2b[i] = f2bf(aw2[i]);
  for (int i = gid; i < 49152; i += gsz) {
    int o = i / 192, k = i % 192;
    AW1b[i] = (k < 130) ? f2bf(aw1[o * 130 + k]) : (u16)0;
  }
}

// =====================================================================
// k_vf — round 7 verbatim (proven).
// =====================================================================
__global__ __launch_bounds__(256) void k_vf(
    const float* __restrict__ sfeat, const u16* __restrict__ FW1h,
    const float* __restrict__ fb1, const float* __restrict__ fs1,
    const float* __restrict__ ft1, const u16* __restrict__ FW2b,
    const float* __restrict__ fb2, u16* __restrict__ vfeat)
{
  __shared__ u16 Hs[128 * 136];
  __shared__ u16 As[128 * 40];
  __shared__ u16 Bs[128 * 40];
  const int tid = threadIdx.x;
  const int row0 = blockIdx.x * 128;
  const int wid = tid >> 6, lane = tid & 63, m16 = lane & 15, quad = lane >> 4;
  const int wr = wid >> 1, wc = wid & 1;
  const int sr = tid >> 1, sk = (tid & 1) * 16;

  f32x4 acc2[4][4];
#pragma unroll
  for (int mt = 0; mt < 4; ++mt)
#pragma unroll
    for (int nt = 0; nt < 4; ++nt) acc2[mt][nt] = (f32x4){0.f, 0.f, 0.f, 0.f};

  for (int h = 0; h < 2; ++h) {
    f32x4 acc[4][4];
#pragma unroll
    for (int mt = 0; mt < 4; ++mt)
#pragma unroll
      for (int nt = 0; nt < 4; ++nt) acc[mt][nt] = (f32x4){0.f, 0.f, 0.f, 0.f};

    for (int s = 0; s < 8; ++s) {
      __syncthreads();
      {
        const float* src = &sfeat[(row0 + sr) * 256 + s * 32 + sk];
        u32 packed[8];
#pragma unroll
        for (int q = 0; q < 4; ++q) {
          float4 v = *(const float4*)&src[q * 4];
          packed[q * 2]     = (u32)f2bf(v.x) | ((u32)f2bf(v.y) << 16);
          packed[q * 2 + 1] = (u32)f2bf(v.z) | ((u32)f2bf(v.w) << 16);
        }
        *(uint4*)&As[sr * 40 + sk]     = *(uint4*)&packed[0];
        *(uint4*)&As[sr * 40 + sk + 8] = *(uint4*)&packed[4];
        const u16* bsrc = &FW1h[(h * 128 + sr) * 256 + s * 32 + sk];
        *(uint4*)&Bs[sr * 40 + sk]     = *(const uint4*)&bsrc[0];
        *(uint4*)&Bs[sr * 40 + sk + 8] = *(const uint4*)&bsrc[8];
      }
      __syncthreads();
#pragma unroll
      for (int mt = 0; mt < 4; ++mt) {
        bf16x8 af = *(const bf16x8*)&As[(wr * 64 + mt * 16 + m16) * 40 + quad * 8];
#pragma unroll
        for (int nt = 0; nt < 4; ++nt) {
          bf16x8 bfr = *(const bf16x8*)&Bs[(wc * 64 + nt * 16 + m16) * 40 + quad * 8];
          acc[mt][nt] = __builtin_amdgcn_mfma_f32_16x16x32_bf16(af, bfr, acc[mt][nt], 0, 0, 0);
        }
      }
    }
    __syncthreads();
#pragma unroll
    for (int nt = 0; nt < 4; ++nt) {
      int colL = wc * 64 + nt * 16 + m16;
      int col = h * 128 + colL;
      float bb = fb1[col], ss = fs1[col], tt = ft1[col];
#pragma unroll
      for (int mt = 0; mt < 4; ++mt) {
        int rL = wr * 64 + mt * 16 + quad * 4;
#pragma unroll
        for (int r = 0; r < 4; ++r)
          Hs[(rL + r) * 136 + colL] = f2bf(fmaxf((acc[mt][nt][r] + bb) * ss + tt, 0.f));
      }
    }
    for (int s2 = 0; s2 < 4; ++s2) {
      __syncthreads();
      {
        const u16* bsrc = &FW2b[sr * 256 + h * 128 + s2 * 32 + sk];
        *(uint4*)&Bs[sr * 40 + sk]     = *(const uint4*)&bsrc[0];
        *(uint4*)&Bs[sr * 40 + sk + 8] = *(const uint4*)&bsrc[8];
      }
      __syncthreads();
#pragma unroll
      for (int mt = 0; mt < 4; ++mt) {
        bf16x8 af = *(const bf16x8*)&Hs[(wr * 64 + mt * 16 + m16) * 136 + s2 * 32 + quad * 8];
#pragma unroll
        for (int nt = 0; nt < 4; ++nt) {
          bf16x8 bfr = *(const bf16x8*)&Bs[(wc * 64 + nt * 16 + m16) * 40 + quad * 8];
          acc2[mt][nt] = __builtin_amdgcn_mfma_f32_16x16x32_bf16(af, bfr, acc2[mt][nt], 0, 0, 0);
        }
      }
    }
  }
#pragma unroll
  for (int nt = 0; nt < 4; ++nt) {
    int col = wc * 64 + nt * 16 + m16;
    float bb = fb2[col];
#pragma unroll
    for (int mt = 0; mt < 4; ++mt) {
      int rbase = row0 + wr * 64 + mt * 16 + quad * 4;
#pragma unroll
      for (int r = 0; r < 4; ++r)
        vfeat[(rbase + r) * 128 + col] = f2bf(acc2[mt][nt][r] + bb);
    }
  }
}

// =====================================================================
// k_agg — round 7 verbatim (proven).
// =====================================================================
__global__ __launch_bounds__(256) void k_agg(
    const float* __restrict__ votes, const u16* __restrict__ vfeat,
    const float* __restrict__ nxyz, const int* __restrict__ gidx,
    const u16* __restrict__ AW1b, const float* __restrict__ ab1,
    const float* __restrict__ as1, const float* __restrict__ at1,
    const u16* __restrict__ AW2b, const float* __restrict__ ab2,
    const float* __restrict__ as2, const float* __restrict__ at2,
    float* __restrict__ pooled)
{
  __shared__ u16 U[32 * 264];
  __shared__ u16 Bs[256 * 72];
  __shared__ int gix[32];
  __shared__ float gvx[32], gvy[32];
  u16* CombA = U;
  u16* As = U;
  float* x2T = (float*)Bs;

  const int bp = blockIdx.x, tid = threadIdx.x, b = bp >> 8;
  if (tid < 32) {
    int g = gidx[bp * 32 + tid];
    gix[tid] = g;
    gvx[tid] = votes[(b * Mn + g) * 2];
    gvy[tid] = votes[(b * Mn + g) * 2 + 1];
  }
  __syncthreads();
  const float sx = nxyz[bp * 2], sy = nxyz[bp * 2 + 1];

  if (tid < 192) {
    int row = tid / 6, c = tid % 6;
    const u16* vsrc = &vfeat[(b * Mn + gix[row]) * 128];
    u16* dst = &CombA[row * 200 + c * 32];
    if (c == 0) {
      dst[0] = f2bf(gvx[row] - sx);
      dst[1] = f2bf(gvy[row] - sy);
      for (int k = 2; k < 32; ++k) dst[k] = vsrc[k - 2];
    } else if (c <= 3) {
      for (int k = 0; k < 32; ++k) dst[k] = vsrc[c * 32 + k - 2];
    } else if (c == 4) {
      dst[0] = vsrc[126]; dst[1] = vsrc[127];
      for (int k = 2; k < 32; ++k) dst[k] = 0;
    } else {
      for (int k = 0; k < 32; ++k) dst[k] = 0;
    }
  }

  const int wid = tid >> 6, lane = tid & 63, m16 = lane & 15, quad = lane >> 4;
  const int mt = wid & 1, nh = wid >> 1;

  f32x4 acc[8];
#pragma unroll
  for (int nt = 0; nt < 8; ++nt) acc[nt] = (f32x4){0.f, 0.f, 0.f, 0.f};
  for (int s = 0; s < 3; ++s) {
    __syncthreads();
    for (int i = tid; i < 4096; i += 256) {
      int n = i >> 4, c4 = i & 15;
      *(uint2*)&Bs[n * 72 + c4 * 4] = *(const uint2*)&AW1b[n * 192 + s * 64 + c4 * 4];
    }
    __syncthreads();
#pragma unroll
    for (int ks = 0; ks < 2; ++ks) {
      bf16x8 af = *(const bf16x8*)&CombA[(mt * 16 + m16) * 200 + s * 64 + ks * 32 + quad * 8];
#pragma unroll
      for (int nt = 0; nt < 8; ++nt) {
        bf16x8 bf_ = *(const bf16x8*)&Bs[(nh * 128 + nt * 16 + m16) * 72 + ks * 32 + quad * 8];
        acc[nt] = __builtin_amdgcn_mfma_f32_16x16x32_bf16(af, bf_, acc[nt], 0, 0, 0);
      }
    }
  }
  __syncthreads();
#pragma unroll
  for (int nt = 0; nt < 8; ++nt) {
    int col = nh * 128 + nt * 16 + m16;
    float bb = ab1[col], ss = as1[col], tt = at1[col];
#pragma unroll
    for (int r = 0; r < 4; ++r) {
      int samp = mt * 16 + quad * 4 + r;
      As[samp * 264 + col] = f2bf(fmaxf((acc[nt][r] + bb) * ss + tt, 0.f));
    }
  }

  f32x4 acc2[8];
#pragma unroll
  for (int nt = 0; nt < 8; ++nt) acc2[nt] = (f32x4){0.f, 0.f, 0.f, 0.f};
  for (int s = 0; s < 4; ++s) {
    __syncthreads();
    for (int i = tid; i < 4096; i += 256) {
      int n = i >> 4, c4 = i & 15;
      *(uint2*)&Bs[n * 72 + c4 * 4] = *(const uint2*)&AW2b[n * 256 + s * 64 + c4 * 4];
    }
    __syncthreads();
#pragma unroll
    for (int ks = 0; ks < 2; ++ks) {
      bf16x8 af = *(const bf16x8*)&As[(mt * 16 + m16) * 264 + s * 64 + ks * 32 + quad * 8];
#pragma unroll
      for (int nt = 0; nt < 8; ++nt) {
        bf16x8 bf_ = *(const bf16x8*)&Bs[(nh * 128 + nt * 16 + m16) * 72 + ks * 32 + quad * 8];
        acc2[nt] = __builtin_amdgcn_mfma_f32_16x16x32_bf16(af, bf_, acc2[nt], 0, 0, 0);
      }
    }
  }
  __syncthreads();
#pragma unroll
  for (int nt = 0; nt < 8; ++nt) {
    int col = nh * 128 + nt * 16 + m16;
    float bb = ab2[col], ss = as2[col], tt = at2[col];
#pragma unroll
    for (int r = 0; r < 4; ++r) {
      int samp = mt * 16 + quad * 4 + r;
      x2T[col * 33 + samp] = fmaxf((acc2[nt][r] + bb) * ss + tt, 0.f);
    }
  }
  __syncthreads();
  {
    float m = x2T[tid * 33];
#pragma unroll
    for (int s2 = 1; s2 < 32; ++s2) m = fmaxf(m, x2T[tid * 33 + s2]);
    pooled[bp * 256 + tid] = m;
  }
}

// =====================================================================
// Proposal head — round 7 verbatim (proven).
// =====================================================================
__global__ __launch_bounds__(256) void k_head(
    const float* __restrict__ pooled,
    const float* __restrict__ pw1, const float* __restrict__ pb1,
    const float* __restrict__ ps1, const float* __restrict__ pt1,
    const float* __restrict__ pw2, const float* __restrict__ pb2,
    const float* __restrict__ ps2, const float* __restrict__ pt2,
    const float* __restrict__ objw, const float* __restrict__ objb,
    const float* __restrict__ clsw, const float* __restrict__ clsb,
    float* __restrict__ out)
{
  __shared__ float xr[256], y1[256], y2[128];
  const int bp = blockIdx.x, tid = threadIdx.x;
  xr[tid] = pooled[bp * 256 + tid];
  __syncthreads();
  {
    float a = 0.f;
    for (int c = 0; c < 256; ++c) a = fmaf(xr[c], pw1[tid * 256 + c], a);
    a = (a + pb1[tid]) * ps1[tid] + pt1[tid];
    y1[tid] = fmaxf(a, 0.f);
  }
  __syncthreads();
  if (tid < 128) {
    float a = 0.f;
    for (int c = 0; c < 256; ++c) a = fmaf(y1[c], pw2[tid * 256 + c], a);
    a = (a + pb2[tid]) * ps2[tid] + pt2[tid];
    y2[tid] = fmaxf(a, 0.f);
  }
  __syncthreads();
  if (tid < 10) {
    float a = 0.f;
    for (int c = 0; c < 128; ++c) a = fmaf(y2[c], clsw[tid * 128 + c], a);
    out[6144 + bp * 10 + tid] = a + clsb[tid];
  } else if (tid == 10) {
    float a = 0.f;
    for (int c = 0; c < 128; ++c) a = fmaf(y2[c], objw[c], a);
    out[4096 + bp] = a + objb[0];
  }
}

// =====================================================================
extern "C" void kernel_launch(void* const* d_in, const int* in_sizes, int n_in,
                              void* d_out, int out_size, void* d_ws, size_t ws_size,
                              hipStream_t stream)
{
  (void)in_sizes; (void)n_in; (void)out_size; (void)ws_size;
  const float* sxyz  = (const float*)d_in[0];
  const float* sfeat = (const float*)d_in[1];
  const float* ow1 = (const float*)d_in[2];
  const float* ob1 = (const float*)d_in[3];
  const float* os1 = (const float*)d_in[4];
  const float* ot1 = (const float*)d_in[5];
  const float* ow2 = (const float*)d_in[6];
  const float* ob2 = (const float*)d_in[7];
  const float* fw1 = (const float*)d_in[8];
  const float* fb1 = (const float*)d_in[9];
  const float* fs1 = (const float*)d_in[10];
  const float* ft1 = (const float*)d_in[11];
  const float* fw2 = (const float*)d_in[12];
  const float* fb2 = (const float*)d_in[13];
  const float* aw1 = (const float*)d_in[14];
  const float* ab1 = (const float*)d_in[15];
  const float* as1 = (const float*)d_in[16];
  const float* at1 = (const float*)d_in[17];
  const float* aw2 = (const float*)d_in[18];
  const float* ab2 = (const float*)d_in[19];
  const float* as2 = (const float*)d_in[20];
  const float* at2 = (const float*)d_in[21];
  const float* pw1 = (const float*)d_in[22];
  const float* pb1 = (const float*)d_in[23];
  const float* ps1 = (const float*)d_in[24];
  const float* pt1 = (const float*)d_in[25];
  const float* pw2 = (const float*)d_in[26];
  const float* pb2 = (const float*)d_in[27];
  const float* ps2 = (const float*)d_in[28];
  const float* pt2 = (const float*)d_in[29];
  const float* objw = (const float*)d_in[30];
  const float* objb = (const float*)d_in[31];
  const float* clsw = (const float*)d_in[32];
  const float* clsb = (const float*)d_in[33];

  char* ws = (char*)d_ws;
  float* votes  = (float*)(ws + 0);             //    524,288
  u16*   vfeat  = (u16*)  (ws + 524288);        // 16,777,216
  float* nxyz   = (float*)(ws + 17301504);      //     16,384
  int*   gidxp  = (int*)  (ws + 17317888);      //    262,144
  float* pooled = (float*)(ws + 17580032);      //  2,097,152
  u16*   FW1h   = (u16*)  (ws + 19677184);      //    131,072
  u16*   FW2b   = (u16*)  (ws + 19808256);      //     65,536
  u16*   AW1b   = (u16*)  (ws + 19873792);      //     98,304
  u16*   AW2b   = (u16*)  (ws + 19972096);      //    131,072
  float* out    = (float*)d_out;

  k_voting_off<<<dim3(2048), dim3(256), 0, stream>>>(
      sxyz, sfeat, ow1, ob1, os1, ot1, ow2, ob2, votes);

  k_fps<<<dim3(8), dim3(512), 0, stream>>>(votes, nxyz, out);

  k_ballq<<<dim3(2048), dim3(256), 0, stream>>>(votes, nxyz, gidxp);

  k_prep<<<dim3(256), dim3(256), 0, stream>>>(
      fw1, fw2, aw1, aw2, FW1h, FW2b, AW1b, AW2b);

  k_vf<<<dim3(512), dim3(256), 0, stream>>>(
      sfeat, FW1h, fb1, fs1, ft1, FW2b, fb2, vfeat);

  k_agg<<<dim3(2048), dim3(256), 0, stream>>>(
      votes, vfeat, nxyz, gidxp, AW1b, ab1, as1, at1,
      AW2b, ab2, as2, at2, pooled);

  k_head<<<dim3(2048), dim3(256), 0, stream>>>(
      pooled, pw1, pb1, ps1, pt1, pw2, pb2, ps2, pt2,
      objw, objb, clsw, clsb, out);
}

// Round 7
// 891.146 us; speedup vs baseline: 1.0900x; 1.0528x over previous
//
#include <hip/hip_runtime.h>

typedef __attribute__((ext_vector_type(8))) short bf16x8;
typedef __attribute__((ext_vector_type(4))) float f32x4;
typedef unsigned short u16;
typedef unsigned int u32;
typedef unsigned long long u64;

#define DEV static __device__ __forceinline__
DEV u16 f2bf(float f) { u32 i = __float_as_uint(f); i += 0x7fffu + ((i >> 16) & 1u); return (u16)(i >> 16); }
DEV float bf2f(u16 u) { return __uint_as_float(((u32)u) << 16); }

constexpr int Mn = 8192;
constexpr int Pn = 256;
constexpr int Kn = 32;
constexpr float R2 = 0.09f;

// =====================================================================
// k_voting_off v3 — round-5 verbatim (proven).
// =====================================================================
__global__ __launch_bounds__(256, 2) void k_voting_off(
    const float* __restrict__ sxyz,   // (65536,2)
    const float* __restrict__ sfeat,  // (65536,256)
    const float* __restrict__ ow1, const float* __restrict__ ob1,
    const float* __restrict__ os1, const float* __restrict__ ot1,
    const float* __restrict__ ow2, const float* __restrict__ ob2,
    float* __restrict__ votes)        // (65536,2)
{
  __shared__ __align__(16) float Xc[16][34];     // [k][row], pad
  __shared__ __align__(16) float Wc[16][262];    // [k][col], pad
  __shared__ __align__(16) float Hst[256][33];   // [col][row], pad

  const int tid = threadIdx.x;
  const int row0 = blockIdx.x * 32;

  const int wv = tid >> 6;        // wave 0..3 -> rows wv*8..wv*8+7
  const int w8 = wv * 8;
  const int cg = tid & 63;        // lane -> cols {2cg,2cg+1,128+2cg,129+2cg}

  float acc[8][4];
#pragma unroll
  for (int r = 0; r < 8; ++r)
#pragma unroll
    for (int j = 0; j < 4; ++j) acc[r][j] = 0.f;

  for (int kc = 0; kc < 16; ++kc) {
    __syncthreads();
    // stage W chunk: Wc[k][o] = ow1[o*256 + kc*16 + k]
    for (int i = tid; i < 256 * 16; i += 256) {
      int o = i >> 4, k = i & 15;
      Wc[k][o] = ow1[o * 256 + kc * 16 + k];
    }
    // stage X chunk: Xc[k][r] = sfeat[(row0+r)*256 + kc*16 + k]
    for (int i = tid; i < 32 * 16; i += 256) {
      int r = i >> 4, k = i & 15;
      Xc[k][r] = sfeat[(row0 + r) * 256 + kc * 16 + k];
    }
    __syncthreads();
#pragma unroll
    for (int k = 0; k < 16; ++k) {
      float2 x01 = *(const float2*)&Xc[k][w8];
      float2 x23 = *(const float2*)&Xc[k][w8 + 2];
      float2 x45 = *(const float2*)&Xc[k][w8 + 4];
      float2 x67 = *(const float2*)&Xc[k][w8 + 6];
      float2 wlo = *(const float2*)&Wc[k][2 * cg];
      float2 whi = *(const float2*)&Wc[k][128 + 2 * cg];
      float x[8] = {x01.x, x01.y, x23.x, x23.y, x45.x, x45.y, x67.x, x67.y};
      float w[4] = {wlo.x, wlo.y, whi.x, whi.y};
#pragma unroll
      for (int r = 0; r < 8; ++r)
#pragma unroll
        for (int j = 0; j < 4; ++j)
          acc[r][j] = fmaf(x[r], w[j], acc[r][j]);
    }
  }
  __syncthreads();
#pragma unroll
  for (int j = 0; j < 4; ++j) {
    int o = (j < 2) ? (2 * cg + j) : (126 + 2 * cg + j);  // j=2:128+2cg, j=3:129+2cg
    float bb = ob1[o], ss = os1[o], tt = ot1[o];
#pragma unroll
    for (int r = 0; r < 8; ++r)
      Hst[o][w8 + r] = fmaxf((acc[r][j] + bb) * ss + tt, 0.f);
  }
  __syncthreads();

  if (tid < 64) {
    int r = tid >> 1, o = tid & 1;
    float a = 0.f;
    for (int k = 0; k < 256; ++k)
      a = fmaf(Hst[k][r], ow2[o * 256 + k], a);
    a += ob2[o];
    int row = row0 + r;
    votes[row * 2 + o] = sxyz[row * 2 + o] + a;
  }
}

// =====================================================================
// k_fps_vf — fused: blocks 0..7 run FPS (v5 verbatim, LDS rebased);
// blocks 8..519 run VF remapped to 8 waves (bit-exact MFMA chains).
//   Rationale (round-5 PMC): fps occupies 8/256 CUs for 240us while the
//   stream serializes vf behind it — yet vf depends only on prep+sfeat.
//   Fusing hides vf entirely under fps.
//   * smem = 86016B static, overlaid per role (fps 68096, vf 55296).
//     84KB => 1 block/CU: vf blocks never co-locate with fps blocks
//     (no LDS/VALU interference with the latency-critical FPS loop);
//     vf gets 8 waves/CU = same as standalone (2 blk x 4 waves).
//   * vf 8-wave remap: wave (wr=wid>>2, wc4=wid&3) owns 64x32 tile,
//     acc[4][2]/acc2[4][2]. Per-output-element accumulation = identical
//     MFMA sequence on identical fragments (same h->s->ks order).
//     Staging redistributed to 512 thr (sr=tid>>2, sk=(tid&3)*8), same
//     final LDS bytes => bit-exact vs proven k_vf.
// =====================================================================
__global__ __launch_bounds__(512) void k_fps_vf(
    const float* __restrict__ votes, float* __restrict__ nxyz,
    float* __restrict__ out,
    const float* __restrict__ sfeat, const u16* __restrict__ FW1h,
    const float* __restrict__ fb1, const float* __restrict__ fs1,
    const float* __restrict__ ft1, const u16* __restrict__ FW2b,
    const float* __restrict__ fb2, u16* __restrict__ vfeat)
{
  __shared__ __align__(16) char smem[86016];
  const int tid = threadIdx.x;

  if (blockIdx.x < 8) {
    // ================= FPS role (proven v5 body) =================
    const int b = blockIdx.x;
    const float* vb = votes + b * Mn * 2;
    float2* xy   = (float2*)smem;                  // 65536 B
    u32*   Sd    = (u32*)(smem + 65536);           // [2][32]
    u32*   Sl    = (u32*)(smem + 65536 + 256);     // [2][32]
    float* histx = (float*)(smem + 66048);
    float* histy = (float*)(smem + 67072);

    {
      const float4* vb4 = (const float4*)vb;
#pragma unroll
      for (int j = tid; j < Mn / 2; j += 512) {
        float4 v = vb4[j];
        *(float4*)&xy[2 * j] = v;
      }
    }
    float dist[16];
#pragma unroll
    for (int s = 0; s < 16; ++s) dist[s] = 1e10f;
    __syncthreads();

    float cx = xy[0].x, cy = xy[0].y;
    if (tid == 0) { histx[0] = cx; histy[0] = cy; }

    for (int it = 1; it < Pn; ++it) {
      float bd = -1.f; int sb = 0;
#pragma unroll
      for (int s = 0; s < 16; ++s) {
        float2 p = xy[s * 512 + tid];
        float dx = p.x - cx, dy = p.y - cy;
        float d = fminf(dist[s], dx * dx + dy * dy);
        dist[s] = d;
        if (d > bd) { bd = d; sb = s; }
      }
      int bi = sb * 512 + tid;

      u32 hd = __float_as_uint(bd), hl = ~(u32)bi;

#define FPS_ROR(VD, VL, N)                                                      \
      {                                                                         \
        u32 od = (u32)__builtin_amdgcn_update_dpp(0, (int)VD, 0x120 + N, 0xF, 0xF, false); \
        u32 ol = (u32)__builtin_amdgcn_update_dpp(0, (int)VL, 0x120 + N, 0xF, 0xF, false); \
        bool g = (od > VD) || (od == VD && ol > VL);                            \
        VD = g ? od : VD; VL = g ? ol : VL;                                     \
      }
      FPS_ROR(hd, hl, 8)
      FPS_ROR(hd, hl, 4)
      FPS_ROR(hd, hl, 2)
      FPS_ROR(hd, hl, 1)

      const int buf = it & 1;
      if ((tid & 15) == 0) {
        int row = tid >> 4;              // 0..31
        Sd[buf * 32 + row] = hd; Sl[buf * 32 + row] = hl;
      }
      __syncthreads();

      int rr = tid & 15;
      u32 rd = Sd[buf * 32 + rr], rl = Sl[buf * 32 + rr];
      {
        u32 od = Sd[buf * 32 + 16 + rr], ol = Sl[buf * 32 + 16 + rr];
        bool g = (od > rd) || (od == rd && ol > rl);
        rd = g ? od : rd; rl = g ? ol : rl;
      }
      FPS_ROR(rd, rl, 8)
      FPS_ROR(rd, rl, 4)
      FPS_ROR(rd, rl, 2)
      FPS_ROR(rd, rl, 1)
#undef FPS_ROR

      int widx = (int)(~rl);
      float2 w = xy[widx];               // uniform addr -> LDS broadcast
      cx = w.x; cy = w.y;
      if (tid == 0) { histx[it] = cx; histy[it] = cy; }
    }
    __syncthreads();
    if (tid < 256) {
      float2 o2; o2.x = histx[tid]; o2.y = histy[tid];
      *(float2*)&nxyz[(b * Pn + tid) * 2] = o2;
      *(float2*)&out[(b * Pn + tid) * 2] = o2;
    }
  } else {
    // ================= VF role (8-wave remap) =================
    const int bx = blockIdx.x - 8;
    const int row0 = bx * 128;
    u16* Hs = (u16*)smem;                  // 128*136*2 = 34816
    u16* As = (u16*)(smem + 34816);        // 128*40*2  = 10240
    u16* Bs = (u16*)(smem + 45056);        // 128*40*2  = 10240

    const int wid = tid >> 6, lane = tid & 63, m16 = lane & 15, quad = lane >> 4;
    const int wr = wid >> 2;        // 0..1 : 64-row group
    const int wc4 = wid & 3;        // 0..3 : 32-col group
    const int sr = tid >> 2, sk = (tid & 3) * 8;

    f32x4 acc2[4][2];
#pragma unroll
    for (int mt = 0; mt < 4; ++mt)
#pragma unroll
      for (int nt = 0; nt < 2; ++nt) acc2[mt][nt] = (f32x4){0.f, 0.f, 0.f, 0.f};

    for (int h = 0; h < 2; ++h) {
      f32x4 acc[4][2];
#pragma unroll
      for (int mt = 0; mt < 4; ++mt)
#pragma unroll
        for (int nt = 0; nt < 2; ++nt) acc[mt][nt] = (f32x4){0.f, 0.f, 0.f, 0.f};

      for (int s = 0; s < 8; ++s) {
        __syncthreads();
        {
          const float* src = &sfeat[(row0 + sr) * 256 + s * 32 + sk];
          float4 v0 = *(const float4*)&src[0];
          float4 v1 = *(const float4*)&src[4];
          u32 packed[4];
          packed[0] = (u32)f2bf(v0.x) | ((u32)f2bf(v0.y) << 16);
          packed[1] = (u32)f2bf(v0.z) | ((u32)f2bf(v0.w) << 16);
          packed[2] = (u32)f2bf(v1.x) | ((u32)f2bf(v1.y) << 16);
          packed[3] = (u32)f2bf(v1.z) | ((u32)f2bf(v1.w) << 16);
          *(uint4*)&As[sr * 40 + sk] = *(uint4*)&packed[0];
          *(uint4*)&Bs[sr * 40 + sk] =
              *(const uint4*)&FW1h[(h * 128 + sr) * 256 + s * 32 + sk];
        }
        __syncthreads();
#pragma unroll
        for (int mt = 0; mt < 4; ++mt) {
          bf16x8 af = *(const bf16x8*)&As[(wr * 64 + mt * 16 + m16) * 40 + quad * 8];
#pragma unroll
          for (int nt = 0; nt < 2; ++nt) {
            bf16x8 bfr = *(const bf16x8*)&Bs[(wc4 * 32 + nt * 16 + m16) * 40 + quad * 8];
            acc[mt][nt] = __builtin_amdgcn_mfma_f32_16x16x32_bf16(af, bfr, acc[mt][nt], 0, 0, 0);
          }
        }
      }
      __syncthreads();
#pragma unroll
      for (int nt = 0; nt < 2; ++nt) {
        int colL = wc4 * 32 + nt * 16 + m16;
        int col = h * 128 + colL;
        float bb = fb1[col], ss = fs1[col], tt = ft1[col];
#pragma unroll
        for (int mt = 0; mt < 4; ++mt) {
          int rL = wr * 64 + mt * 16 + quad * 4;
#pragma unroll
          for (int r = 0; r < 4; ++r)
            Hs[(rL + r) * 136 + colL] = f2bf(fmaxf((acc[mt][nt][r] + bb) * ss + tt, 0.f));
        }
      }
      for (int s2 = 0; s2 < 4; ++s2) {
        __syncthreads();
        {
          *(uint4*)&Bs[sr * 40 + sk] =
              *(const uint4*)&FW2b[sr * 256 + h * 128 + s2 * 32 + sk];
        }
        __syncthreads();
#pragma unroll
        for (int mt = 0; mt < 4; ++mt) {
          bf16x8 af = *(const bf16x8*)&Hs[(wr * 64 + mt * 16 + m16) * 136 + s2 * 32 + quad * 8];
#pragma unroll
          for (int nt = 0; nt < 2; ++nt) {
            bf16x8 bfr = *(const bf16x8*)&Bs[(wc4 * 32 + nt * 16 + m16) * 40 + quad * 8];
            acc2[mt][nt] = __builtin_amdgcn_mfma_f32_16x16x32_bf16(af, bfr, acc2[mt][nt], 0, 0, 0);
          }
        }
      }
    }
#pragma unroll
    for (int nt = 0; nt < 2; ++nt) {
      int col = wc4 * 32 + nt * 16 + m16;
      float bb = fb2[col];
#pragma unroll
      for (int mt = 0; mt < 4; ++mt) {
        int rbase = row0 + wr * 64 + mt * 16 + quad * 4;
#pragma unroll
        for (int r = 0; r < 4; ++r)
          vfeat[(rbase + r) * 128 + col] = f2bf(acc2[mt][nt][r] + bb);
      }
    }
  }
}

// =====================================================================
// Ball query — round 7 verbatim (proven).
// =====================================================================
__global__ __launch_bounds__(256) void k_ballq(
    const float* __restrict__ votes, const float* __restrict__ nxyz,
    int* __restrict__ gidx)
{
  const int bp = blockIdx.x, tid = threadIdx.x;
  const int b = bp >> 8;
  const float* vb = votes + b * Mn * 2;
  const float sx = nxyz[bp * 2], sy = nxyz[bp * 2 + 1];
  const float a = sx * sx + sy * sy;
  float d2[32];
#pragma unroll
  for (int s = 0; s < 32; ++s) {
    int i = tid * 32 + s;
    float x = vb[i * 2], y = vb[i * 2 + 1];
    d2[s] = (a + (x * x + y * y)) - 2.f * (sx * x + sy * y);
  }
  __shared__ float sd[4];
  __shared__ int si[4];
  __shared__ int swi;
  unsigned mask = 0;
  for (int kk = 0; kk < Kn; ++kk) {
    float bd = 3.4e38f; int bi = 0x7fffffff;
#pragma unroll
    for (int s = 0; s < 32; ++s)
      if (!((mask >> s) & 1u) && d2[s] < bd) { bd = d2[s]; bi = tid * 32 + s; }
#pragma unroll
    for (int off = 32; off > 0; off >>= 1) {
      float od = __shfl_xor(bd, off);
      int oi = __shfl_xor(bi, off);
      if (od < bd || (od == bd && oi < bi)) { bd = od; bi = oi; }
    }
    if ((tid & 63) == 0) { sd[tid >> 6] = bd; si[tid >> 6] = bi; }
    __syncthreads();
    if (tid == 0) {
#pragma unroll
      for (int w = 1; w < 4; ++w)
        if (sd[w] < bd || (sd[w] == bd && si[w] < bi)) { bd = sd[w]; bi = si[w]; }
      swi = bi;
      gidx[bp * Kn + kk] = (bd > R2) ? 0 : bi;
    }
    __syncthreads();
    int wi = swi;
    if ((wi >> 5) == tid) mask |= 1u << (wi & 31);
  }
}

// =====================================================================
// Prep: bf16 weight conversions. No deps -> launched first.
// =====================================================================
__global__ __launch_bounds__(256) void k_prep(
    const float* __restrict__ fw1, const float* __restrict__ fw2,
    const float* __restrict__ aw1, const float* __restrict__ aw2,
    u16* __restrict__ FW1h, u16* __restrict__ FW2b,
    u16* __restrict__ AW1b, u16* __restrict__ AW2b)
{
  const int gid = blockIdx.x * 256 + threadIdx.x;
  const int gsz = gridDim.x * 256;
  for (int i = gid; i < 65536; i += gsz) FW1h[i] = f2bf(fw1[i]);
  for (int i = gid; i < 32768; i += gsz) FW2b[i] = f2bf(fw2[i]);
  for (int i = gid; i < 65536; i += gsz) AW2b[i] = f2bf(aw2[i]);
  for (int i = gid; i < 49152; i += gsz) {
    int o = i / 192, k = i % 192;
    AW1b[i] = (k < 130) ? f2bf(aw1[o * 130 + k]) : (u16)0;
  }
}

// =====================================================================
// k_agg — round 7 verbatim (proven).
// =====================================================================
__global__ __launch_bounds__(256) void k_agg(
    const float* __restrict__ votes, const u16* __restrict__ vfeat,
    const float* __restrict__ nxyz, const int* __restrict__ gidx,
    const u16* __restrict__ AW1b, const float* __restrict__ ab1,
    const float* __restrict__ as1, const float* __restrict__ at1,
    const u16* __restrict__ AW2b, const float* __restrict__ ab2,
    const float* __restrict__ as2, const float* __restrict__ at2,
    float* __restrict__ pooled)
{
  __shared__ u16 U[32 * 264];
  __shared__ u16 Bs[256 * 72];
  __shared__ int gix[32];
  __shared__ float gvx[32], gvy[32];
  u16* CombA = U;
  u16* As = U;
  float* x2T = (float*)Bs;

  const int bp = blockIdx.x, tid = threadIdx.x, b = bp >> 8;
  if (tid < 32) {
    int g = gidx[bp * 32 + tid];
    gix[tid] = g;
    gvx[tid] = votes[(b * Mn + g) * 2];
    gvy[tid] = votes[(b * Mn + g) * 2 + 1];
  }
  __syncthreads();
  const float sx = nxyz[bp * 2], sy = nxyz[bp * 2 + 1];

  if (tid < 192) {
    int row = tid / 6, c = tid % 6;
    const u16* vsrc = &vfeat[(b * Mn + gix[row]) * 128];
    u16* dst = &CombA[row * 200 + c * 32];
    if (c == 0) {
      dst[0] = f2bf(gvx[row] - sx);
      dst[1] = f2bf(gvy[row] - sy);
      for (int k = 2; k < 32; ++k) dst[k] = vsrc[k - 2];
    } else if (c <= 3) {
      for (int k = 0; k < 32; ++k) dst[k] = vsrc[c * 32 + k - 2];
    } else if (c == 4) {
      dst[0] = vsrc[126]; dst[1] = vsrc[127];
      for (int k = 2; k < 32; ++k) dst[k] = 0;
    } else {
      for (int k = 0; k < 32; ++k) dst[k] = 0;
    }
  }

  const int wid = tid >> 6, lane = tid & 63, m16 = lane & 15, quad = lane >> 4;
  const int mt = wid & 1, nh = wid >> 1;

  f32x4 acc[8];
#pragma unroll
  for (int nt = 0; nt < 8; ++nt) acc[nt] = (f32x4){0.f, 0.f, 0.f, 0.f};
  for (int s = 0; s < 3; ++s) {
    __syncthreads();
    for (int i = tid; i < 4096; i += 256) {
      int n = i >> 4, c4 = i & 15;
      *(uint2*)&Bs[n * 72 + c4 * 4] = *(const uint2*)&AW1b[n * 192 + s * 64 + c4 * 4];
    }
    __syncthreads();
#pragma unroll
    for (int ks = 0; ks < 2; ++ks) {
      bf16x8 af = *(const bf16x8*)&CombA[(mt * 16 + m16) * 200 + s * 64 + ks * 32 + quad * 8];
#pragma unroll
      for (int nt = 0; nt < 8; ++nt) {
        bf16x8 bf_ = *(const bf16x8*)&Bs[(nh * 128 + nt * 16 + m16) * 72 + ks * 32 + quad * 8];
        acc[nt] = __builtin_amdgcn_mfma_f32_16x16x32_bf16(af, bf_, acc[nt], 0, 0, 0);
      }
    }
  }
  __syncthreads();
#pragma unroll
  for (int nt = 0; nt < 8; ++nt) {
    int col = nh * 128 + nt * 16 + m16;
    float bb = ab1[col], ss = as1[col], tt = at1[col];
#pragma unroll
    for (int r = 0; r < 4; ++r) {
      int samp = mt * 16 + quad * 4 + r;
      As[samp * 264 + col] = f2bf(fmaxf((acc[nt][r] + bb) * ss + tt, 0.f));
    }
  }

  f32x4 acc2[8];
#pragma unroll
  for (int nt = 0; nt < 8; ++nt) acc2[nt] = (f32x4){0.f, 0.f, 0.f, 0.f};
  for (int s = 0; s < 4; ++s) {
    __syncthreads();
    for (int i = tid; i < 4096; i += 256) {
      int n = i >> 4, c4 = i & 15;
      *(uint2*)&Bs[n * 72 + c4 * 4] = *(const uint2*)&AW2b[n * 256 + s * 64 + c4 * 4];
    }
    __syncthreads();
#pragma unroll
    for (int ks = 0; ks < 2; ++ks) {
      bf16x8 af = *(const bf16x8*)&As[(mt * 16 + m16) * 264 + s * 64 + ks * 32 + quad * 8];
#pragma unroll
      for (int nt = 0; nt < 8; ++nt) {
        bf16x8 bf_ = *(const bf16x8*)&Bs[(nh * 128 + nt * 16 + m16) * 72 + ks * 32 + quad * 8];
        acc2[nt] = __builtin_amdgcn_mfma_f32_16x16x32_bf16(af, bf_, acc2[nt], 0, 0, 0);
      }
    }
  }
  __syncthreads();
#pragma unroll
  for (int nt = 0; nt < 8; ++nt) {
    int col = nh * 128 + nt * 16 + m16;
    float bb = ab2[col], ss = as2[col], tt = at2[col];
#pragma unroll
    for (int r = 0; r < 4; ++r) {
      int samp = mt * 16 + quad * 4 + r;
      x2T[col * 33 + samp] = fmaxf((acc2[nt][r] + bb) * ss + tt, 0.f);
    }
  }
  __syncthreads();
  {
    float m = x2T[tid * 33];
#pragma unroll
    for (int s2 = 1; s2 < 32; ++s2) m = fmaxf(m, x2T[tid * 33 + s2]);
    pooled[bp * 256 + tid] = m;
  }
}

// =====================================================================
// Proposal head — round 7 verbatim (proven).
// =====================================================================
__global__ __launch_bounds__(256) void k_head(
    const float* __restrict__ pooled,
    const float* __restrict__ pw1, const float* __restrict__ pb1,
    const float* __restrict__ ps1, const float* __restrict__ pt1,
    const float* __restrict__ pw2, const float* __restrict__ pb2,
    const float* __restrict__ ps2, const float* __restrict__ pt2,
    const float* __restrict__ objw, const float* __restrict__ objb,
    const float* __restrict__ clsw, const float* __restrict__ clsb,
    float* __restrict__ out)
{
  __shared__ float xr[256], y1[256], y2[128];
  const int bp = blockIdx.x, tid = threadIdx.x;
  xr[tid] = pooled[bp * 256 + tid];
  __syncthreads();
  {
    float a = 0.f;
    for (int c = 0; c < 256; ++c) a = fmaf(xr[c], pw1[tid * 256 + c], a);
    a = (a + pb1[tid]) * ps1[tid] + pt1[tid];
    y1[tid] = fmaxf(a, 0.f);
  }
  __syncthreads();
  if (tid < 128) {
    float a = 0.f;
    for (int c = 0; c < 256; ++c) a = fmaf(y1[c], pw2[tid * 256 + c], a);
    a = (a + pb2[tid]) * ps2[tid] + pt2[tid];
    y2[tid] = fmaxf(a, 0.f);
  }
  __syncthreads();
  if (tid < 10) {
    float a = 0.f;
    for (int c = 0; c < 128; ++c) a = fmaf(y2[c], clsw[tid * 128 + c], a);
    out[6144 + bp * 10 + tid] = a + clsb[tid];
  } else if (tid == 10) {
    float a = 0.f;
    for (int c = 0; c < 128; ++c) a = fmaf(y2[c], objw[c], a);
    out[4096 + bp] = a + objb[0];
  }
}

// =====================================================================
extern "C" void kernel_launch(void* const* d_in, const int* in_sizes, int n_in,
                              void* d_out, int out_size, void* d_ws, size_t ws_size,
                              hipStream_t stream)
{
  (void)in_sizes; (void)n_in; (void)out_size; (void)ws_size;
  const float* sxyz  = (const float*)d_in[0];
  const float* sfeat = (const float*)d_in[1];
  const float* ow1 = (const float*)d_in[2];
  const float* ob1 = (const float*)d_in[3];
  const float* os1 = (const float*)d_in[4];
  const float* ot1 = (const float*)d_in[5];
  const float* ow2 = (const float*)d_in[6];
  const float* ob2 = (const float*)d_in[7];
  const float* fw1 = (const float*)d_in[8];
  const float* fb1 = (const float*)d_in[9];
  const float* fs1 = (const float*)d_in[10];
  const float* ft1 = (const float*)d_in[11];
  const float* fw2 = (const float*)d_in[12];
  const float* fb2 = (const float*)d_in[13];
  const float* aw1 = (const float*)d_in[14];
  const float* ab1 = (const float*)d_in[15];
  const float* as1 = (const float*)d_in[16];
  const float* at1 = (const float*)d_in[17];
  const float* aw2 = (const float*)d_in[18];
  const float* ab2 = (const float*)d_in[19];
  const float* as2 = (const float*)d_in[20];
  const float* at2 = (const float*)d_in[21];
  const float* pw1 = (const float*)d_in[22];
  const float* pb1 = (const float*)d_in[23];
  const float* ps1 = (const float*)d_in[24];
  const float* pt1 = (const float*)d_in[25];
  const float* pw2 = (const float*)d_in[26];
  const float* pb2 = (const float*)d_in[27];
  const float* ps2 = (const float*)d_in[28];
  const float* pt2 = (const float*)d_in[29];
  const float* objw = (const float*)d_in[30];
  const float* objb = (const float*)d_in[31];
  const float* clsw = (const float*)d_in[32];
  const float* clsb = (const float*)d_in[33];

  char* ws = (char*)d_ws;
  float* votes  = (float*)(ws + 0);             //    524,288
  u16*   vfeat  = (u16*)  (ws + 524288);        // 16,777,216
  float* nxyz   = (float*)(ws + 17301504);      //     16,384
  int*   gidxp  = (int*)  (ws + 17317888);      //    262,144
  float* pooled = (float*)(ws + 17580032);      //  2,097,152
  u16*   FW1h   = (u16*)  (ws + 19677184);      //    131,072
  u16*   FW2b   = (u16*)  (ws + 19808256);      //     65,536
  u16*   AW1b   = (u16*)  (ws + 19873792);      //     98,304
  u16*   AW2b   = (u16*)  (ws + 19972096);      //    131,072
  float* out    = (float*)d_out;

  // prep first (no deps) so vf-role blocks of the fused kernel are ready
  k_prep<<<dim3(256), dim3(256), 0, stream>>>(
      fw1, fw2, aw1, aw2, FW1h, FW2b, AW1b, AW2b);

  k_voting_off<<<dim3(2048), dim3(256), 0, stream>>>(
      sxyz, sfeat, ow1, ob1, os1, ot1, ow2, ob2, votes);

  // fused: blocks 0..7 = FPS (one per batch), blocks 8..519 = VF
  k_fps_vf<<<dim3(520), dim3(512), 0, stream>>>(
      votes, nxyz, out,
      sfeat, FW1h, fb1, fs1, ft1, FW2b, fb2, vfeat);

  k_ballq<<<dim3(2048), dim3(256), 0, stream>>>(votes, nxyz, gidxp);

  k_agg<<<dim3(2048), dim3(256), 0, stream>>>(
      votes, vfeat, nxyz, gidxp, AW1b, ab1, as1, at1,
      AW2b, ab2, as2, at2, pooled);

  k_head<<<dim3(2048), dim3(256), 0, stream>>>(
      pooled, pw1, pb1, ps1, pt1, pw2, pb2, ps2, pt2,
      objw, objb, clsw, clsb, out);
}

// Round 8
// 854.940 us; speedup vs baseline: 1.1361x; 1.0423x over previous
//
#include <hip/hip_runtime.h>

typedef __attribute__((ext_vector_type(8))) short bf16x8;
typedef __attribute__((ext_vector_type(4))) float f32x4;
typedef unsigned short u16;
typedef unsigned int u32;
typedef unsigned long long u64;

#define DEV static __device__ __forceinline__
DEV u16 f2bf(float f) { u32 i = __float_as_uint(f); i += 0x7fffu + ((i >> 16) & 1u); return (u16)(i >> 16); }
DEV float bf2f(u16 u) { return __uint_as_float(((u32)u) << 16); }

constexpr int Mn = 8192;
constexpr int Pn = 256;
constexpr int Kn = 32;
constexpr float R2 = 0.09f;

// =====================================================================
// k_voting_off v4 — 8x8 register blocking, b128 LDS reads.
//   Round-7 model: v3 was LDS-issue-bound (6 ds_read_b64 per 32 FMA;
//   per-CU LDS pipe ~2.3x oversubscribed vs FMA issue) — which is why
//   the conflict fix alone didn't move time. v4: 64 rows/block
//   (grid 1024), each thread 8 rows x 8 cols (acc[8][8]); per k-step
//   4x ds_read_b128 (2 broadcast x + 2 lane-consecutive w) feed 64
//   FMAs -> LDS ops/FMA drop 2.7x; W-staging per output row halves.
//   Strides: Xc[16][68], Wc[16][260] (68%32=4, 260%32=4 -> staging
//   writes 2-way aliased = free; reads 16B-aligned). LDS unioned:
//   {Xc,Wc} (21KB) then Hst[256][67] (68.6KB) -> 2 blocks/CU.
//   Bit-exact: per-(row,col) ascending-k fmaf chain, identical
//   epilogue expr, identical serial 256-chain tail (128 threads).
// =====================================================================
__global__ __launch_bounds__(256, 2) void k_voting_off(
    const float* __restrict__ sxyz,   // (65536,2)
    const float* __restrict__ sfeat,  // (65536,256)
    const float* __restrict__ ow1, const float* __restrict__ ob1,
    const float* __restrict__ os1, const float* __restrict__ ot1,
    const float* __restrict__ ow2, const float* __restrict__ ob2,
    float* __restrict__ votes)        // (65536,2)
{
  __shared__ __align__(16) char vsm[68608];
  float (*Xc)[68]  = (float(*)[68])vsm;             // 16x68x4  = 4352
  float (*Wc)[260] = (float(*)[260])(vsm + 4352);   // 16x260x4 = 16640
  float (*Hst)[67] = (float(*)[67])vsm;             // 256x67x4 = 68608 (union)

  const int tid = threadIdx.x;
  const int row0 = blockIdx.x * 64;
  const int wv = tid >> 6, lane = tid & 63;
  const int rr = wv * 16 + (lane >> 5) * 8;   // thread's first row (mult of 8)
  const int c4 = (lane & 31) * 4;             // first col of low group

  float acc[8][8];
#pragma unroll
  for (int r = 0; r < 8; ++r)
#pragma unroll
    for (int j = 0; j < 8; ++j) acc[r][j] = 0.f;

  for (int kc = 0; kc < 16; ++kc) {
    __syncthreads();
    // stage W chunk: Wc[k][o] = ow1[o*256 + kc*16 + k]
    for (int i = tid; i < 256 * 16; i += 256) {
      int o = i >> 4, k = i & 15;
      Wc[k][o] = ow1[o * 256 + kc * 16 + k];
    }
    // stage X chunk: Xc[k][r] = sfeat[(row0+r)*256 + kc*16 + k]
    for (int i = tid; i < 64 * 16; i += 256) {
      int r = i >> 4, k = i & 15;
      Xc[k][r] = sfeat[(row0 + r) * 256 + kc * 16 + k];
    }
    __syncthreads();
#pragma unroll
    for (int k = 0; k < 16; ++k) {
      float4 x0 = *(const float4*)&Xc[k][rr];        // rows rr..rr+3 (broadcast)
      float4 x1 = *(const float4*)&Xc[k][rr + 4];    // rows rr+4..rr+7
      float4 w0 = *(const float4*)&Wc[k][c4];        // cols c4..c4+3
      float4 w1 = *(const float4*)&Wc[k][128 + c4];  // cols 128+c4..+3
      float x[8] = {x0.x, x0.y, x0.z, x0.w, x1.x, x1.y, x1.z, x1.w};
      float w[8] = {w0.x, w0.y, w0.z, w0.w, w1.x, w1.y, w1.z, w1.w};
#pragma unroll
      for (int r = 0; r < 8; ++r)
#pragma unroll
        for (int j = 0; j < 8; ++j)
          acc[r][j] = fmaf(x[r], w[j], acc[r][j]);
    }
  }
  __syncthreads();   // Xc/Wc dead; reuse union as Hst
#pragma unroll
  for (int j = 0; j < 8; ++j) {
    int o = (j < 4) ? (c4 + j) : (124 + c4 + j);  // j>=4: 128 + c4 + (j-4)
    float bb = ob1[o], ss = os1[o], tt = ot1[o];
#pragma unroll
    for (int r = 0; r < 8; ++r)
      Hst[o][rr + r] = fmaxf((acc[r][j] + bb) * ss + tt, 0.f);
  }
  __syncthreads();

  if (tid < 128) {
    int r = tid >> 1, o = tid & 1;
    float a = 0.f;
    for (int k = 0; k < 256; ++k)
      a = fmaf(Hst[k][r], ow2[o * 256 + k], a);
    a += ob2[o];
    int row = row0 + r;
    votes[row * 2 + o] = sxyz[row * 2 + o] + a;
  }
}

// =====================================================================
// k_fps_vf — round-7 verbatim (proven, 249us; vf fully hidden).
// =====================================================================
__global__ __launch_bounds__(512) void k_fps_vf(
    const float* __restrict__ votes, float* __restrict__ nxyz,
    float* __restrict__ out,
    const float* __restrict__ sfeat, const u16* __restrict__ FW1h,
    const float* __restrict__ fb1, const float* __restrict__ fs1,
    const float* __restrict__ ft1, const u16* __restrict__ FW2b,
    const float* __restrict__ fb2, u16* __restrict__ vfeat)
{
  __shared__ __align__(16) char smem[86016];
  const int tid = threadIdx.x;

  if (blockIdx.x < 8) {
    // ================= FPS role (proven v5 body) =================
    const int b = blockIdx.x;
    const float* vb = votes + b * Mn * 2;
    float2* xy   = (float2*)smem;                  // 65536 B
    u32*   Sd    = (u32*)(smem + 65536);           // [2][32]
    u32*   Sl    = (u32*)(smem + 65536 + 256);     // [2][32]
    float* histx = (float*)(smem + 66048);
    float* histy = (float*)(smem + 67072);

    {
      const float4* vb4 = (const float4*)vb;
#pragma unroll
      for (int j = tid; j < Mn / 2; j += 512) {
        float4 v = vb4[j];
        *(float4*)&xy[2 * j] = v;
      }
    }
    float dist[16];
#pragma unroll
    for (int s = 0; s < 16; ++s) dist[s] = 1e10f;
    __syncthreads();

    float cx = xy[0].x, cy = xy[0].y;
    if (tid == 0) { histx[0] = cx; histy[0] = cy; }

    for (int it = 1; it < Pn; ++it) {
      float bd = -1.f; int sb = 0;
#pragma unroll
      for (int s = 0; s < 16; ++s) {
        float2 p = xy[s * 512 + tid];
        float dx = p.x - cx, dy = p.y - cy;
        float d = fminf(dist[s], dx * dx + dy * dy);
        dist[s] = d;
        if (d > bd) { bd = d; sb = s; }
      }
      int bi = sb * 512 + tid;

      u32 hd = __float_as_uint(bd), hl = ~(u32)bi;

#define FPS_ROR(VD, VL, N)                                                      \
      {                                                                         \
        u32 od = (u32)__builtin_amdgcn_update_dpp(0, (int)VD, 0x120 + N, 0xF, 0xF, false); \
        u32 ol = (u32)__builtin_amdgcn_update_dpp(0, (int)VL, 0x120 + N, 0xF, 0xF, false); \
        bool g = (od > VD) || (od == VD && ol > VL);                            \
        VD = g ? od : VD; VL = g ? ol : VL;                                     \
      }
      FPS_ROR(hd, hl, 8)
      FPS_ROR(hd, hl, 4)
      FPS_ROR(hd, hl, 2)
      FPS_ROR(hd, hl, 1)

      const int buf = it & 1;
      if ((tid & 15) == 0) {
        int row = tid >> 4;              // 0..31
        Sd[buf * 32 + row] = hd; Sl[buf * 32 + row] = hl;
      }
      __syncthreads();

      int rr = tid & 15;
      u32 rd = Sd[buf * 32 + rr], rl = Sl[buf * 32 + rr];
      {
        u32 od = Sd[buf * 32 + 16 + rr], ol = Sl[buf * 32 + 16 + rr];
        bool g = (od > rd) || (od == rd && ol > rl);
        rd = g ? od : rd; rl = g ? ol : rl;
      }
      FPS_ROR(rd, rl, 8)
      FPS_ROR(rd, rl, 4)
      FPS_ROR(rd, rl, 2)
      FPS_ROR(rd, rl, 1)
#undef FPS_ROR

      int widx = (int)(~rl);
      float2 w = xy[widx];               // uniform addr -> LDS broadcast
      cx = w.x; cy = w.y;
      if (tid == 0) { histx[it] = cx; histy[it] = cy; }
    }
    __syncthreads();
    if (tid < 256) {
      float2 o2; o2.x = histx[tid]; o2.y = histy[tid];
      *(float2*)&nxyz[(b * Pn + tid) * 2] = o2;
      *(float2*)&out[(b * Pn + tid) * 2] = o2;
    }
  } else {
    // ================= VF role (8-wave remap) =================
    const int bx = blockIdx.x - 8;
    const int row0 = bx * 128;
    u16* Hs = (u16*)smem;                  // 128*136*2 = 34816
    u16* As = (u16*)(smem + 34816);        // 128*40*2  = 10240
    u16* Bs = (u16*)(smem + 45056);        // 128*40*2  = 10240

    const int wid = tid >> 6, lane = tid & 63, m16 = lane & 15, quad = lane >> 4;
    const int wr = wid >> 2;        // 0..1 : 64-row group
    const int wc4 = wid & 3;        // 0..3 : 32-col group
    const int sr = tid >> 2, sk = (tid & 3) * 8;

    f32x4 acc2[4][2];
#pragma unroll
    for (int mt = 0; mt < 4; ++mt)
#pragma unroll
      for (int nt = 0; nt < 2; ++nt) acc2[mt][nt] = (f32x4){0.f, 0.f, 0.f, 0.f};

    for (int h = 0; h < 2; ++h) {
      f32x4 acc[4][2];
#pragma unroll
      for (int mt = 0; mt < 4; ++mt)
#pragma unroll
        for (int nt = 0; nt < 2; ++nt) acc[mt][nt] = (f32x4){0.f, 0.f, 0.f, 0.f};

      for (int s = 0; s < 8; ++s) {
        __syncthreads();
        {
          const float* src = &sfeat[(row0 + sr) * 256 + s * 32 + sk];
          float4 v0 = *(const float4*)&src[0];
          float4 v1 = *(const float4*)&src[4];
          u32 packed[4];
          packed[0] = (u32)f2bf(v0.x) | ((u32)f2bf(v0.y) << 16);
          packed[1] = (u32)f2bf(v0.z) | ((u32)f2bf(v0.w) << 16);
          packed[2] = (u32)f2bf(v1.x) | ((u32)f2bf(v1.y) << 16);
          packed[3] = (u32)f2bf(v1.z) | ((u32)f2bf(v1.w) << 16);
          *(uint4*)&As[sr * 40 + sk] = *(uint4*)&packed[0];
          *(uint4*)&Bs[sr * 40 + sk] =
              *(const uint4*)&FW1h[(h * 128 + sr) * 256 + s * 32 + sk];
        }
        __syncthreads();
#pragma unroll
        for (int mt = 0; mt < 4; ++mt) {
          bf16x8 af = *(const bf16x8*)&As[(wr * 64 + mt * 16 + m16) * 40 + quad * 8];
#pragma unroll
          for (int nt = 0; nt < 2; ++nt) {
            bf16x8 bfr = *(const bf16x8*)&Bs[(wc4 * 32 + nt * 16 + m16) * 40 + quad * 8];
            acc[mt][nt] = __builtin_amdgcn_mfma_f32_16x16x32_bf16(af, bfr, acc[mt][nt], 0, 0, 0);
          }
        }
      }
      __syncthreads();
#pragma unroll
      for (int nt = 0; nt < 2; ++nt) {
        int colL = wc4 * 32 + nt * 16 + m16;
        int col = h * 128 + colL;
        float bb = fb1[col], ss = fs1[col], tt = ft1[col];
#pragma unroll
        for (int mt = 0; mt < 4; ++mt) {
          int rL = wr * 64 + mt * 16 + quad * 4;
#pragma unroll
          for (int r = 0; r < 4; ++r)
            Hs[(rL + r) * 136 + colL] = f2bf(fmaxf((acc[mt][nt][r] + bb) * ss + tt, 0.f));
        }
      }
      for (int s2 = 0; s2 < 4; ++s2) {
        __syncthreads();
        {
          *(uint4*)&Bs[sr * 40 + sk] =
              *(const uint4*)&FW2b[sr * 256 + h * 128 + s2 * 32 + sk];
        }
        __syncthreads();
#pragma unroll
        for (int mt = 0; mt < 4; ++mt) {
          bf16x8 af = *(const bf16x8*)&Hs[(wr * 64 + mt * 16 + m16) * 136 + s2 * 32 + quad * 8];
#pragma unroll
          for (int nt = 0; nt < 2; ++nt) {
            bf16x8 bfr = *(const bf16x8*)&Bs[(wc4 * 32 + nt * 16 + m16) * 40 + quad * 8];
            acc2[mt][nt] = __builtin_amdgcn_mfma_f32_16x16x32_bf16(af, bfr, acc2[mt][nt], 0, 0, 0);
          }
        }
      }
    }
#pragma unroll
    for (int nt = 0; nt < 2; ++nt) {
      int col = wc4 * 32 + nt * 16 + m16;
      float bb = fb2[col];
#pragma unroll
      for (int mt = 0; mt < 4; ++mt) {
        int rbase = row0 + wr * 64 + mt * 16 + quad * 4;
#pragma unroll
        for (int r = 0; r < 4; ++r)
          vfeat[(rbase + r) * 128 + col] = f2bf(acc2[mt][nt][r] + bb);
      }
    }
  }
}

// =====================================================================
// Ball query — round 7 verbatim (proven).
// =====================================================================
__global__ __launch_bounds__(256) void k_ballq(
    const float* __restrict__ votes, const float* __restrict__ nxyz,
    int* __restrict__ gidx)
{
  const int bp = blockIdx.x, tid = threadIdx.x;
  const int b = bp >> 8;
  const float* vb = votes + b * Mn * 2;
  const float sx = nxyz[bp * 2], sy = nxyz[bp * 2 + 1];
  const float a = sx * sx + sy * sy;
  float d2[32];
#pragma unroll
  for (int s = 0; s < 32; ++s) {
    int i = tid * 32 + s;
    float x = vb[i * 2], y = vb[i * 2 + 1];
    d2[s] = (a + (x * x + y * y)) - 2.f * (sx * x + sy * y);
  }
  __shared__ float sd[4];
  __shared__ int si[4];
  __shared__ int swi;
  unsigned mask = 0;
  for (int kk = 0; kk < Kn; ++kk) {
    float bd = 3.4e38f; int bi = 0x7fffffff;
#pragma unroll
    for (int s = 0; s < 32; ++s)
      if (!((mask >> s) & 1u) && d2[s] < bd) { bd = d2[s]; bi = tid * 32 + s; }
#pragma unroll
    for (int off = 32; off > 0; off >>= 1) {
      float od = __shfl_xor(bd, off);
      int oi = __shfl_xor(bi, off);
      if (od < bd || (od == bd && oi < bi)) { bd = od; bi = oi; }
    }
    if ((tid & 63) == 0) { sd[tid >> 6] = bd; si[tid >> 6] = bi; }
    __syncthreads();
    if (tid == 0) {
#pragma unroll
      for (int w = 1; w < 4; ++w)
        if (sd[w] < bd || (sd[w] == bd && si[w] < bi)) { bd = sd[w]; bi = si[w]; }
      swi = bi;
      gidx[bp * Kn + kk] = (bd > R2) ? 0 : bi;
    }
    __syncthreads();
    int wi = swi;
    if ((wi >> 5) == tid) mask |= 1u << (wi & 31);
  }
}

// =====================================================================
// Prep: bf16 weight conversions. No deps -> launched first.
// =====================================================================
__global__ __launch_bounds__(256) void k_prep(
    const float* __restrict__ fw1, const float* __restrict__ fw2,
    const float* __restrict__ aw1, const float* __restrict__ aw2,
    u16* __restrict__ FW1h, u16* __restrict__ FW2b,
    u16* __restrict__ AW1b, u16* __restrict__ AW2b)
{
  const int gid = blockIdx.x * 256 + threadIdx.x;
  const int gsz = gridDim.x * 256;
  for (int i = gid; i < 65536; i += gsz) FW1h[i] = f2bf(fw1[i]);
  for (int i = gid; i < 32768; i += gsz) FW2b[i] = f2bf(fw2[i]);
  for (int i = gid; i < 65536; i += gsz) AW2b[i] = f2bf(aw2[i]);
  for (int i = gid; i < 49152; i += gsz) {
    int o = i / 192, k = i % 192;
    AW1b[i] = (k < 130) ? f2bf(aw1[o * 130 + k]) : (u16)0;
  }
}

// =====================================================================
// k_agg_head — k_agg (proven) with k_head fused onto the tail.
//   head's input pooled[bp*256+..] is produced by exactly this block;
//   keep it in LDS (xr aliased onto the dead U region), run the
//   identical head arithmetic, drop one launch + the 2MB pooled
//   round-trip. Values bit-identical (same fp32 registers).
// =====================================================================
__global__ __launch_bounds__(256) void k_agg_head(
    const float* __restrict__ votes, const u16* __restrict__ vfeat,
    const float* __restrict__ nxyz, const int* __restrict__ gidx,
    const u16* __restrict__ AW1b, const float* __restrict__ ab1,
    const float* __restrict__ as1, const float* __restrict__ at1,
    const u16* __restrict__ AW2b, const float* __restrict__ ab2,
    const float* __restrict__ as2, const float* __restrict__ at2,
    const float* __restrict__ pw1, const float* __restrict__ pb1,
    const float* __restrict__ ps1, const float* __restrict__ pt1,
    const float* __restrict__ pw2, const float* __restrict__ pb2,
    const float* __restrict__ ps2, const float* __restrict__ pt2,
    const float* __restrict__ objw, const float* __restrict__ objb,
    const float* __restrict__ clsw, const float* __restrict__ clsb,
    float* __restrict__ out)
{
  __shared__ u16 U[32 * 264];
  __shared__ u16 Bs[256 * 72];
  __shared__ int gix[32];
  __shared__ float gvx[32], gvy[32];
  u16* CombA = U;
  u16* As = U;
  float* x2T = (float*)Bs;
  float* xr = (float*)U;          // head buffers aliased on dead U
  float* y1 = ((float*)U) + 256;
  float* y2 = ((float*)U) + 512;

  const int bp = blockIdx.x, tid = threadIdx.x, b = bp >> 8;
  if (tid < 32) {
    int g = gidx[bp * 32 + tid];
    gix[tid] = g;
    gvx[tid] = votes[(b * Mn + g) * 2];
    gvy[tid] = votes[(b * Mn + g) * 2 + 1];
  }
  __syncthreads();
  const float sx = nxyz[bp * 2], sy = nxyz[bp * 2 + 1];

  if (tid < 192) {
    int row = tid / 6, c = tid % 6;
    const u16* vsrc = &vfeat[(b * Mn + gix[row]) * 128];
    u16* dst = &CombA[row * 200 + c * 32];
    if (c == 0) {
      dst[0] = f2bf(gvx[row] - sx);
      dst[1] = f2bf(gvy[row] - sy);
      for (int k = 2; k < 32; ++k) dst[k] = vsrc[k - 2];
    } else if (c <= 3) {
      for (int k = 0; k < 32; ++k) dst[k] = vsrc[c * 32 + k - 2];
    } else if (c == 4) {
      dst[0] = vsrc[126]; dst[1] = vsrc[127];
      for (int k = 2; k < 32; ++k) dst[k] = 0;
    } else {
      for (int k = 0; k < 32; ++k) dst[k] = 0;
    }
  }

  const int wid = tid >> 6, lane = tid & 63, m16 = lane & 15, quad = lane >> 4;
  const int mt = wid & 1, nh = wid >> 1;

  f32x4 acc[8];
#pragma unroll
  for (int nt = 0; nt < 8; ++nt) acc[nt] = (f32x4){0.f, 0.f, 0.f, 0.f};
  for (int s = 0; s < 3; ++s) {
    __syncthreads();
    for (int i = tid; i < 4096; i += 256) {
      int n = i >> 4, c4 = i & 15;
      *(uint2*)&Bs[n * 72 + c4 * 4] = *(const uint2*)&AW1b[n * 192 + s * 64 + c4 * 4];
    }
    __syncthreads();
#pragma unroll
    for (int ks = 0; ks < 2; ++ks) {
      bf16x8 af = *(const bf16x8*)&CombA[(mt * 16 + m16) * 200 + s * 64 + ks * 32 + quad * 8];
#pragma unroll
      for (int nt = 0; nt < 8; ++nt) {
        bf16x8 bf_ = *(const bf16x8*)&Bs[(nh * 128 + nt * 16 + m16) * 72 + ks * 32 + quad * 8];
        acc[nt] = __builtin_amdgcn_mfma_f32_16x16x32_bf16(af, bf_, acc[nt], 0, 0, 0);
      }
    }
  }
  __syncthreads();
#pragma unroll
  for (int nt = 0; nt < 8; ++nt) {
    int col = nh * 128 + nt * 16 + m16;
    float bb = ab1[col], ss = as1[col], tt = at1[col];
#pragma unroll
    for (int r = 0; r < 4; ++r) {
      int samp = mt * 16 + quad * 4 + r;
      As[samp * 264 + col] = f2bf(fmaxf((acc[nt][r] + bb) * ss + tt, 0.f));
    }
  }

  f32x4 acc2[8];
#pragma unroll
  for (int nt = 0; nt < 8; ++nt) acc2[nt] = (f32x4){0.f, 0.f, 0.f, 0.f};
  for (int s = 0; s < 4; ++s) {
    __syncthreads();
    for (int i = tid; i < 4096; i += 256) {
      int n = i >> 4, c4 = i & 15;
      *(uint2*)&Bs[n * 72 + c4 * 4] = *(const uint2*)&AW2b[n * 256 + s * 64 + c4 * 4];
    }
    __syncthreads();
#pragma unroll
    for (int ks = 0; ks < 2; ++ks) {
      bf16x8 af = *(const bf16x8*)&As[(mt * 16 + m16) * 264 + s * 64 + ks * 32 + quad * 8];
#pragma unroll
      for (int nt = 0; nt < 8; ++nt) {
        bf16x8 bf_ = *(const bf16x8*)&Bs[(nh * 128 + nt * 16 + m16) * 72 + ks * 32 + quad * 8];
        acc2[nt] = __builtin_amdgcn_mfma_f32_16x16x32_bf16(af, bf_, acc2[nt], 0, 0, 0);
      }
    }
  }
  __syncthreads();
#pragma unroll
  for (int nt = 0; nt < 8; ++nt) {
    int col = nh * 128 + nt * 16 + m16;
    float bb = ab2[col], ss = as2[col], tt = at2[col];
#pragma unroll
    for (int r = 0; r < 4; ++r) {
      int samp = mt * 16 + quad * 4 + r;
      x2T[col * 33 + samp] = fmaxf((acc2[nt][r] + bb) * ss + tt, 0.f);
    }
  }
  __syncthreads();     // As (U) reads done before this; U now dead
  {
    float m = x2T[tid * 33];
#pragma unroll
    for (int s2 = 1; s2 < 32; ++s2) m = fmaxf(m, x2T[tid * 33 + s2]);
    xr[tid] = m;       // == pooled[bp*256+tid], bit-exact
  }
  __syncthreads();

  // ---- head (identical arithmetic to proven k_head) ----
  {
    float a = 0.f;
    for (int c = 0; c < 256; ++c) a = fmaf(xr[c], pw1[tid * 256 + c], a);
    a = (a + pb1[tid]) * ps1[tid] + pt1[tid];
    y1[tid] = fmaxf(a, 0.f);
  }
  __syncthreads();
  if (tid < 128) {
    float a = 0.f;
    for (int c = 0; c < 256; ++c) a = fmaf(y1[c], pw2[tid * 256 + c], a);
    a = (a + pb2[tid]) * ps2[tid] + pt2[tid];
    y2[tid] = fmaxf(a, 0.f);
  }
  __syncthreads();
  if (tid < 10) {
    float a = 0.f;
    for (int c = 0; c < 128; ++c) a = fmaf(y2[c], clsw[tid * 128 + c], a);
    out[6144 + bp * 10 + tid] = a + clsb[tid];
  } else if (tid == 10) {
    float a = 0.f;
    for (int c = 0; c < 128; ++c) a = fmaf(y2[c], objw[c], a);
    out[4096 + bp] = a + objb[0];
  }
}

// =====================================================================
extern "C" void kernel_launch(void* const* d_in, const int* in_sizes, int n_in,
                              void* d_out, int out_size, void* d_ws, size_t ws_size,
                              hipStream_t stream)
{
  (void)in_sizes; (void)n_in; (void)out_size; (void)ws_size;
  const float* sxyz  = (const float*)d_in[0];
  const float* sfeat = (const float*)d_in[1];
  const float* ow1 = (const float*)d_in[2];
  const float* ob1 = (const float*)d_in[3];
  const float* os1 = (const float*)d_in[4];
  const float* ot1 = (const float*)d_in[5];
  const float* ow2 = (const float*)d_in[6];
  const float* ob2 = (const float*)d_in[7];
  const float* fw1 = (const float*)d_in[8];
  const float* fb1 = (const float*)d_in[9];
  const float* fs1 = (const float*)d_in[10];
  const float* ft1 = (const float*)d_in[11];
  const float* fw2 = (const float*)d_in[12];
  const float* fb2 = (const float*)d_in[13];
  const float* aw1 = (const float*)d_in[14];
  const float* ab1 = (const float*)d_in[15];
  const float* as1 = (const float*)d_in[16];
  const float* at1 = (const float*)d_in[17];
  const float* aw2 = (const float*)d_in[18];
  const float* ab2 = (const float*)d_in[19];
  const float* as2 = (const float*)d_in[20];
  const float* at2 = (const float*)d_in[21];
  const float* pw1 = (const float*)d_in[22];
  const float* pb1 = (const float*)d_in[23];
  const float* ps1 = (const float*)d_in[24];
  const float* pt1 = (const float*)d_in[25];
  const float* pw2 = (const float*)d_in[26];
  const float* pb2 = (const float*)d_in[27];
  const float* ps2 = (const float*)d_in[28];
  const float* pt2 = (const float*)d_in[29];
  const float* objw = (const float*)d_in[30];
  const float* objb = (const float*)d_in[31];
  const float* clsw = (const float*)d_in[32];
  const float* clsb = (const float*)d_in[33];

  char* ws = (char*)d_ws;
  float* votes  = (float*)(ws + 0);             //    524,288
  u16*   vfeat  = (u16*)  (ws + 524288);        // 16,777,216
  float* nxyz   = (float*)(ws + 17301504);      //     16,384
  int*   gidxp  = (int*)  (ws + 17317888);      //    262,144
  u16*   FW1h   = (u16*)  (ws + 19677184);      //    131,072
  u16*   FW2b   = (u16*)  (ws + 19808256);      //     65,536
  u16*   AW1b   = (u16*)  (ws + 19873792);      //     98,304
  u16*   AW2b   = (u16*)  (ws + 19972096);      //    131,072
  float* out    = (float*)d_out;

  // prep first (no deps) so vf-role blocks of the fused kernel are ready
  k_prep<<<dim3(256), dim3(256), 0, stream>>>(
      fw1, fw2, aw1, aw2, FW1h, FW2b, AW1b, AW2b);

  k_voting_off<<<dim3(1024), dim3(256), 0, stream>>>(
      sxyz, sfeat, ow1, ob1, os1, ot1, ow2, ob2, votes);

  // fused: blocks 0..7 = FPS (one per batch), blocks 8..519 = VF
  k_fps_vf<<<dim3(520), dim3(512), 0, stream>>>(
      votes, nxyz, out,
      sfeat, FW1h, fb1, fs1, ft1, FW2b, fb2, vfeat);

  k_ballq<<<dim3(2048), dim3(256), 0, stream>>>(votes, nxyz, gidxp);

  k_agg_head<<<dim3(2048), dim3(256), 0, stream>>>(
      votes, vfeat, nxyz, gidxp, AW1b, ab1, as1, at1,
      AW2b, ab2, as2, at2,
      pw1, pb1, ps1, pt1, pw2, pb2, ps2, pt2,
      objw, objb, clsw, clsb, out);
}